// Round 1
// baseline (810.282 us; speedup 1.0000x reference)
//
#include <hip/hip_runtime.h>
#include <stdint.h>

typedef unsigned int u32;
typedef unsigned long long u64;

#define K_PRE 2048
#define MAX_DET 100
#define NBATCH 4
#define NCLS 10
#define NH 512
#define NW 512
#define HWSZ (NH*NW)          // 262144 = 2^18
#define CHW (NCLS*HWSZ)       // 2621440
#define NELEM (NBATCH*CHW)    // 10485760
#define NVEC (NELEM/4)

// ---------------- workspace layout (bytes) ----------------
#define HIST_OFF   0                       // 65536 u32 = 262144 B
#define META_OFF   262144                  // 64 u32
#define CANDA_OFF  262400                  // 2048 u64
#define CANDE_OFF  (CANDA_OFF + 2048*8)    // 4096 u64
#define ARR_BASE   (CANDE_OFF + 4096*8)    // 14 arrays of 2048*4B
#define MASK_OFF   (ARR_BASE + 14*8192)    // 2048*32 u64 = 524288 B
// total ~950KB

__device__ __forceinline__ u32*  ws_hist(char* ws)  { return (u32*)(ws + HIST_OFF); }
__device__ __forceinline__ u32*  ws_meta(char* ws)  { return (u32*)(ws + META_OFF); }
__device__ __forceinline__ u64*  ws_candA(char* ws) { return (u64*)(ws + CANDA_OFF); }
__device__ __forceinline__ u64*  ws_candE(char* ws) { return (u64*)(ws + CANDE_OFF); }
// arrays: 0=score 1=x 2=y 3=z 4=w 5=l 6=h 7=yaw 8=lox 9=loy 10=hix 11=hiy 12=area
__device__ __forceinline__ float* ws_arr(char* ws, int i) { return (float*)(ws + ARR_BASE + i*8192); }
__device__ __forceinline__ u32*  ws_lv(char* ws)    { return (u32*)(ws + ARR_BASE + 13*8192); }
__device__ __forceinline__ u64*  ws_mask(char* ws)  { return (u64*)(ws + MASK_OFF); }

__device__ __forceinline__ int bucket_of(float v) {
    int b = (int)(v * 65536.0f);
    b = b < 0 ? 0 : (b > 65535 ? 65535 : b);
    return b;
}

__device__ __forceinline__ u64 shfl_u64(u64 v, int lane) {
    int lo = __shfl((int)(v & 0xffffffffull), lane);
    int hi = __shfl((int)(v >> 32), lane);
    return ((u64)(u32)hi << 32) | (u32)lo;
}

// ---------------- 1. histogram ----------------
__global__ __launch_bounds__(256) void k_hist(const float* __restrict__ cls, char* ws) {
    u32* hist = ws_hist(ws);
    int gid = blockIdx.x * blockDim.x + threadIdx.x;
    int stride = gridDim.x * blockDim.x;
    const float4* cv = (const float4*)cls;
    for (int v = gid; v < NVEC; v += stride) {
        float4 f = cv[v];
        atomicAdd(&hist[bucket_of(f.x)], 1u);
        atomicAdd(&hist[bucket_of(f.y)], 1u);
        atomicAdd(&hist[bucket_of(f.z)], 1u);
        atomicAdd(&hist[bucket_of(f.w)], 1u);
    }
}

// ---------------- 2. find threshold bucket ----------------
__global__ __launch_bounds__(1024) void k_scan(char* ws) {
    u32* hist = ws_hist(ws);
    u32* meta = ws_meta(ws);
    __shared__ u32 suf[1024];
    __shared__ int sg;
    __shared__ u32 sR;
    int tid = threadIdx.x;
    u32 s = 0;
    int base = tid * 64;
    for (int k = 0; k < 64; ++k) s += hist[base + k];
    suf[tid] = s;
    __syncthreads();
    for (int off = 1; off < 1024; off <<= 1) {
        u32 add = (tid + off < 1024) ? suf[tid + off] : 0u;
        __syncthreads();
        suf[tid] += add;
        __syncthreads();
    }
    bool c0 = suf[tid] >= K_PRE;
    bool c1 = (tid < 1023) ? (suf[tid + 1] >= K_PRE) : false;
    if (c0 && !c1) { sg = tid; sR = (tid < 1023) ? suf[tid + 1] : 0u; }
    __syncthreads();
    if (tid == 0) {
        int g = sg;
        u32 R = sR;
        int B1 = g * 64;
        u32 ng1 = R;
        for (int b = 63; b >= 0; --b) {
            u32 h = hist[g * 64 + b];
            if (R + h >= K_PRE) { B1 = g * 64 + b; ng1 = R; break; }
            R += h;
        }
        meta[0] = (u32)B1;       // threshold bucket
        meta[1] = ng1;           // count strictly above
        meta[2] = K_PRE - ng1;   // NEED from boundary bucket
    }
}

// ---------------- 3. compact candidates ----------------
__global__ __launch_bounds__(256) void k_compact(const float* __restrict__ cls, char* ws) {
    u32* meta = ws_meta(ws);
    u64* cA = ws_candA(ws);
    u64* cE = ws_candE(ws);
    const int B1 = (int)meta[0];
    int gid = blockIdx.x * blockDim.x + threadIdx.x;
    int stride = gridDim.x * blockDim.x;
    const float4* cv = (const float4*)cls;
    for (int v = gid; v < NVEC; v += stride) {
        float4 f = cv[v];
        float vals[4] = {f.x, f.y, f.z, f.w};
        #pragma unroll
        for (int c = 0; c < 4; ++c) {
            int bkt = bucket_of(vals[c]);
            if (bkt >= B1) {
                u32 idx = (u32)(4 * v + c);
                u32 bits = __float_as_uint(vals[c]);
                u32 u = (bits & 0x80000000u) ? ~bits : (bits | 0x80000000u);
                u64 key = ((u64)u << 32) | (u32)(~idx);
                if (bkt > B1) {
                    u32 p = atomicAdd(&meta[3], 1u);
                    if (p < K_PRE) cA[p] = key;
                } else {
                    u32 p = atomicAdd(&meta[4], 1u);
                    if (p < 4096) cE[p] = key;
                }
            }
        }
    }
}

// ---------------- 4. resolve boundary + full sort ----------------
__device__ void bitonic_desc(u64* s, int N) {
    int tid = threadIdx.x;
    for (int k = 2; k <= N; k <<= 1) {
        for (int j = k >> 1; j > 0; j >>= 1) {
            __syncthreads();
            for (int i = tid; i < N; i += blockDim.x) {
                int ixj = i ^ j;
                if (ixj > i) {
                    u64 a = s[i], b = s[ixj];
                    bool sw = ((i & k) == 0) ? (a < b) : (a > b);
                    if (sw) { s[i] = b; s[ixj] = a; }
                }
            }
        }
    }
    __syncthreads();
}

__global__ __launch_bounds__(1024) void k_select(char* ws) {
    __shared__ u64 sk[4096];
    u32* meta = ws_meta(ws);
    u64* cA = ws_candA(ws);
    u64* cE = ws_candE(ws);
    int tid = threadIdx.x;
    u32 NE = meta[4]; if (NE > 4096u) NE = 4096u;
    u32 NEED = meta[2];
    u32 NG1 = meta[1];
    for (int t = tid; t < 4096; t += 1024) sk[t] = (t < (int)NE) ? cE[t] : 0ull;
    bitonic_desc(sk, 4096);
    for (int t = tid; t < (int)NEED; t += 1024) cA[NG1 + t] = sk[t];
    __syncthreads();
    for (int t = tid; t < K_PRE; t += 1024) sk[t] = cA[t];
    bitonic_desc(sk, K_PRE);
    for (int t = tid; t < K_PRE; t += 1024) cA[t] = sk[t];
}

// ---------------- 5. decode boxes ----------------
__global__ __launch_bounds__(256) void k_decode(const float* __restrict__ bbox, char* ws) {
    int r = blockIdx.x * blockDim.x + threadIdx.x;
    if (r >= K_PRE) return;
    u64 key = ws_candA(ws)[r];
    u32 u = (u32)(key >> 32);
    u32 idx = ~((u32)key);
    if (idx >= NELEM) idx = NELEM - 1;  // safety (pathological pads only)
    u32 bits = (u & 0x80000000u) ? (u ^ 0x80000000u) : ~u;
    float sc = __uint_as_float(bits);
    int b = idx / CHW;
    u32 rem = idx - (u32)b * CHW;
    int c = (int)(rem >> 18);
    u32 rem2 = rem & 0x3FFFFu;
    int h = (int)(rem2 >> 9);
    int w = (int)(rem2 & 511u);
    const float* bp = bbox + (size_t)b * (7 * HWSZ) + rem2;
    float p0 = bp[0 * HWSZ];
    float p1 = bp[1 * HWSZ];
    float p2 = bp[2 * HWSZ];
    float p3 = bp[3 * HWSZ];
    float p4 = bp[4 * HWSZ];
    float p5 = bp[5 * HWSZ];
    float p6 = bp[6 * HWSZ];
    float x = (-51.2f + ((float)w + 0.5f) * 0.2f) + p0;
    float y = (-51.2f + ((float)h + 0.5f) * 0.2f) + p1;
    float bw = expf(p3), bl = expf(p4), bh = expf(p5);
    ws_arr(ws, 0)[r] = sc;
    ws_arr(ws, 1)[r] = x;
    ws_arr(ws, 2)[r] = y;
    ws_arr(ws, 3)[r] = p2;
    ws_arr(ws, 4)[r] = bw;
    ws_arr(ws, 5)[r] = bl;
    ws_arr(ws, 6)[r] = bh;
    ws_arr(ws, 7)[r] = p6;
    float hw = bw * 0.5f, hl = bl * 0.5f;
    ws_arr(ws, 8)[r]  = x - hw;
    ws_arr(ws, 9)[r]  = y - hl;
    ws_arr(ws, 10)[r] = x + hw;
    ws_arr(ws, 11)[r] = y + hl;
    ws_arr(ws, 12)[r] = bw * bl;
    ws_lv(ws)[r] = (u32)c | ((sc > 0.3f) ? 256u : 0u);
}

// ---------------- 6. suppression bit-matrix ----------------
__global__ __launch_bounds__(256) void k_suppmat(char* ws) {
    __shared__ float slox[2048], sloy[2048], shix[2048], shiy[2048], sarea[2048];
    __shared__ u32 slv[2048];
    int tid = threadIdx.x;
    for (int i = tid; i < K_PRE; i += 256) {
        slox[i] = ws_arr(ws, 8)[i];
        sloy[i] = ws_arr(ws, 9)[i];
        shix[i] = ws_arr(ws, 10)[i];
        shiy[i] = ws_arr(ws, 11)[i];
        sarea[i] = ws_arr(ws, 12)[i];
        slv[i] = ws_lv(ws)[i];
    }
    __syncthreads();
    int r = tid >> 5, wj = tid & 31;
    int i = blockIdx.x * 8 + r;
    float lx = slox[i], ly = sloy[i], hx = shix[i], hy = shiy[i], ar = sarea[i];
    u32 li = slv[i] & 0xffu;
    u64 bits = 0;
    for (int s = 0; s < 64; ++s) {
        int off = (s + wj) & 63;       // rotate to avoid LDS bank conflicts
        int j = wj * 64 + off;
        u32 lvj = slv[j];
        bool cnd = (j > i) && ((lvj & 0xffu) == li) && ((lvj >> 8) != 0u);
        if (cnd) {
            float iw = fminf(hx, shix[j]) - fmaxf(lx, slox[j]); iw = fmaxf(iw, 0.0f);
            float ih = fminf(hy, shiy[j]) - fmaxf(ly, sloy[j]); ih = fmaxf(ih, 0.0f);
            float inter = iw * ih;
            float un = (ar + sarea[j] - inter) + 1e-6f;
            cnd = (inter / un) >= 0.5f;
        }
        bits |= ((u64)(cnd ? 1u : 0u)) << off;
    }
    ws_mask(ws)[(size_t)i * 32 + wj] = bits;
}

// ---------------- 7. sequential greedy NMS + emit ----------------
#define NMS_CHUNK 112
#define NMS_NCH 19   // ceil(2048/112)
__global__ __launch_bounds__(1024) void k_nms(char* ws, float* __restrict__ out) {
    u64* mask = ws_mask(ws);
    u32* lv = ws_lv(ws);
    float* score = ws_arr(ws, 0);
    __shared__ u64 rowbuf[2][NMS_CHUNK * 32];
    __shared__ u64 validMask[32];
    __shared__ u64 keepMask[32];
    __shared__ u32 sT;
    int tid = threadIdx.x;
    if (tid < 32) validMask[tid] = 0ull;
    __syncthreads();
    for (int i = tid; i < K_PRE; i += 1024)
        if ((lv[i] >> 8) & 1u) atomicOr(&validMask[i >> 6], 1ull << (i & 63));
    __syncthreads();
    // preload chunk 0
    for (int e = tid; e < NMS_CHUNK * 32; e += 1024) rowbuf[0][e] = mask[e];
    __syncthreads();
    u64 remv = 0ull;
    u64 validLocal = (tid < 64) ? validMask[tid & 31] : 0ull;
    for (int t = 0; t < NMS_NCH; ++t) {
        int base = t * NMS_CHUNK;
        int rows = (base + NMS_CHUNK <= K_PRE) ? NMS_CHUNK : (K_PRE - base);
        if (tid >= 64 && t + 1 < NMS_NCH) {
            int nb = (t + 1) * NMS_CHUNK;
            int nrows = (nb + NMS_CHUNK <= K_PRE) ? NMS_CHUNK : (K_PRE - nb);
            for (int e = tid - 64; e < nrows * 32; e += (1024 - 64))
                rowbuf[(t + 1) & 1][e] = mask[(size_t)nb * 32 + e];
        }
        if (tid < 64) {
            int lane = tid & 31;
            const u64* rb = rowbuf[t & 1];
            for (int ii = 0; ii < rows; ++ii) {
                int i = base + ii;
                u64 aw = shfl_u64(validLocal & ~remv, i >> 6);
                int kp = (int)((aw >> (i & 63)) & 1ull);
                u64 row = rb[ii * 32 + lane];
                if (kp) remv |= row;
            }
        }
        __syncthreads();
    }
    if (tid < 32) keepMask[tid] = validMask[tid] & ~remv;
    __syncthreads();
    if (tid == 0) {
        u32 T = 0;
        for (int w = 0; w < 32; ++w) T += (u32)__popcll(keepMask[w]);
        sT = T;
    }
    __syncthreads();
    u32 T = sT;
    for (int i = tid; i < K_PRE; i += 1024) {
        u64 km = keepMask[i >> 6];
        int bi = i & 63;
        int kp = (int)((km >> bi) & 1ull);
        int rk = 0;
        for (int w = 0; w < (i >> 6); ++w) rk += (int)__popcll(keepMask[w]);
        rk += (int)__popcll(bi ? (km & ((1ull << bi) - 1ull)) : 0ull);
        int slot = -1;
        if (kp) {
            if (rk < MAX_DET) slot = rk;
        } else if ((int)T < MAX_DET) {
            int f = (int)T + (i - rk);
            if (f < MAX_DET) slot = f;
        }
        if (slot >= 0) {
            #pragma unroll
            for (int k = 0; k < 7; ++k)
                out[slot * 8 + k] = kp ? ws_arr(ws, 1 + k)[i] : 0.0f;
            out[slot * 8 + 7] = kp ? score[i] : 0.0f;
            out[8 * MAX_DET + slot] = (float)(lv[i] & 0xffu);
            out[9 * MAX_DET + slot] = kp ? 1.0f : 0.0f;
        }
    }
}

extern "C" void kernel_launch(void* const* d_in, const int* in_sizes, int n_in,
                              void* d_out, int out_size, void* d_ws, size_t ws_size,
                              hipStream_t stream) {
    const float* cls = (const float*)d_in[0];
    const float* bbox = (const float*)d_in[1];
    float* out = (float*)d_out;
    char* ws = (char*)d_ws;
    // zero histogram + meta (counters)
    hipMemsetAsync(ws, 0, 262144 + 256, stream);
    k_hist<<<2560, 256, 0, stream>>>(cls, ws);
    k_scan<<<1, 1024, 0, stream>>>(ws);
    k_compact<<<2560, 256, 0, stream>>>(cls, ws);
    k_select<<<1, 1024, 0, stream>>>(ws);
    k_decode<<<8, 256, 0, stream>>>(bbox, ws);
    k_suppmat<<<256, 256, 0, stream>>>(ws);
    k_nms<<<1, 1024, 0, stream>>>(ws, out);
}

// Round 2
// 445.525 us; speedup vs baseline: 1.8187x; 1.8187x over previous
//
#include <hip/hip_runtime.h>
#include <stdint.h>

typedef unsigned int u32;
typedef unsigned long long u64;

#define K_PRE 2048
#define MAX_DET 100
#define NBATCH 4
#define NCLS 10
#define NH 512
#define NW 512
#define HWSZ (NH*NW)          // 262144 = 2^18
#define CHW (NCLS*HWSZ)       // 2621440
#define NELEM (NBATCH*CHW)    // 10485760
#define NVEC (NELEM/4)
#define NHIST 4096

// ---------------- workspace layout (bytes) ----------------
#define HIST_OFF   0                       // 4096 u32 = 16384 B
#define META_OFF   16384                   // 64 u32
#define CANDA_OFF  16640                   // 2048 u64
#define CANDE_OFF  (CANDA_OFF + 2048*8)    // 4096 u64
#define ARR_BASE   (CANDE_OFF + 4096*8)    // 14 arrays of 2048*4B
#define MASK_OFF   (ARR_BASE + 14*8192)    // 2048*32 u64 = 524288 B
// total ~705KB

__device__ __forceinline__ u32*  ws_hist(char* ws)  { return (u32*)(ws + HIST_OFF); }
__device__ __forceinline__ u32*  ws_meta(char* ws)  { return (u32*)(ws + META_OFF); }
__device__ __forceinline__ u64*  ws_candA(char* ws) { return (u64*)(ws + CANDA_OFF); }
__device__ __forceinline__ u64*  ws_candE(char* ws) { return (u64*)(ws + CANDE_OFF); }
// arrays: 0=score 1=x 2=y 3=z 4=w 5=l 6=h 7=yaw 8=lox 9=loy 10=hix 11=hiy 12=area
__device__ __forceinline__ float* ws_arr(char* ws, int i) { return (float*)(ws + ARR_BASE + i*8192); }
__device__ __forceinline__ u32*  ws_lv(char* ws)    { return (u32*)(ws + ARR_BASE + 13*8192); }
__device__ __forceinline__ u64*  ws_mask(char* ws)  { return (u64*)(ws + MASK_OFF); }

__device__ __forceinline__ int bucket_of(float v) {
    int b = (int)(v * (float)NHIST);
    b = b < 0 ? 0 : (b > NHIST - 1 ? NHIST - 1 : b);
    return b;
}

__device__ __forceinline__ u64 shfl_u64(u64 v, int lane) {
    int lo = __shfl((int)(v & 0xffffffffull), lane);
    int hi = __shfl((int)(v >> 32), lane);
    return ((u64)(u32)hi << 32) | (u32)lo;
}

// ---------------- 1. histogram (LDS-privatized) ----------------
__global__ __launch_bounds__(512) void k_hist(const float* __restrict__ cls, char* ws) {
    __shared__ u32 lh[NHIST];
    int tid = threadIdx.x;
    for (int i = tid; i < NHIST; i += 512) lh[i] = 0u;
    __syncthreads();
    int gid = blockIdx.x * 512 + tid;
    int stride = gridDim.x * 512;
    const float4* cv = (const float4*)cls;
    for (int v = gid; v < NVEC; v += stride) {
        float4 f = cv[v];
        atomicAdd(&lh[bucket_of(f.x)], 1u);
        atomicAdd(&lh[bucket_of(f.y)], 1u);
        atomicAdd(&lh[bucket_of(f.z)], 1u);
        atomicAdd(&lh[bucket_of(f.w)], 1u);
    }
    __syncthreads();
    u32* hist = ws_hist(ws);
    for (int i = tid; i < NHIST; i += 512) {
        u32 c = lh[i];
        if (c) atomicAdd(&hist[i], c);
    }
}

// ---------------- 2. find threshold bucket ----------------
__global__ __launch_bounds__(1024) void k_scan(char* ws) {
    u32* hist = ws_hist(ws);
    u32* meta = ws_meta(ws);
    __shared__ u32 suf[1024];
    __shared__ int sg;
    __shared__ u32 sR;
    int tid = threadIdx.x;
    u32 s = 0;
    int base = tid * 4;
    #pragma unroll
    for (int k = 0; k < 4; ++k) s += hist[base + k];
    suf[tid] = s;
    __syncthreads();
    for (int off = 1; off < 1024; off <<= 1) {
        u32 add = (tid + off < 1024) ? suf[tid + off] : 0u;
        __syncthreads();
        suf[tid] += add;
        __syncthreads();
    }
    bool c0 = suf[tid] >= K_PRE;
    bool c1 = (tid < 1023) ? (suf[tid + 1] >= K_PRE) : false;
    if (c0 && !c1) { sg = tid; sR = (tid < 1023) ? suf[tid + 1] : 0u; }
    __syncthreads();
    if (tid == 0) {
        int g = sg;
        u32 R = sR;
        int B1 = g * 4;
        u32 ng1 = R;
        for (int b = 3; b >= 0; --b) {
            u32 h = hist[g * 4 + b];
            if (R + h >= K_PRE) { B1 = g * 4 + b; ng1 = R; break; }
            R += h;
        }
        meta[0] = (u32)B1;       // threshold bucket
        meta[1] = ng1;           // count strictly above
        meta[2] = K_PRE - ng1;   // NEED from boundary bucket
    }
}

// ---------------- 3. compact candidates ----------------
__global__ __launch_bounds__(256) void k_compact(const float* __restrict__ cls, char* ws) {
    u32* meta = ws_meta(ws);
    u64* cA = ws_candA(ws);
    u64* cE = ws_candE(ws);
    const int B1 = (int)meta[0];
    int gid = blockIdx.x * blockDim.x + threadIdx.x;
    int stride = gridDim.x * blockDim.x;
    const float4* cv = (const float4*)cls;
    for (int v = gid; v < NVEC; v += stride) {
        float4 f = cv[v];
        float vals[4] = {f.x, f.y, f.z, f.w};
        #pragma unroll
        for (int c = 0; c < 4; ++c) {
            int bkt = bucket_of(vals[c]);
            if (bkt >= B1) {
                u32 idx = (u32)(4 * v + c);
                u32 bits = __float_as_uint(vals[c]);
                u32 u = (bits & 0x80000000u) ? ~bits : (bits | 0x80000000u);
                u64 key = ((u64)u << 32) | (u32)(~idx);
                if (bkt > B1) {
                    u32 p = atomicAdd(&meta[3], 1u);
                    if (p < K_PRE) cA[p] = key;
                } else {
                    u32 p = atomicAdd(&meta[4], 1u);
                    if (p < 4096) cE[p] = key;
                }
            }
        }
    }
}

// ---------------- 4. resolve boundary + full sort ----------------
__device__ void bitonic_desc(u64* s, int N) {
    int tid = threadIdx.x;
    for (int k = 2; k <= N; k <<= 1) {
        for (int j = k >> 1; j > 0; j >>= 1) {
            __syncthreads();
            for (int i = tid; i < N; i += blockDim.x) {
                int ixj = i ^ j;
                if (ixj > i) {
                    u64 a = s[i], b = s[ixj];
                    bool sw = ((i & k) == 0) ? (a < b) : (a > b);
                    if (sw) { s[i] = b; s[ixj] = a; }
                }
            }
        }
    }
    __syncthreads();
}

__global__ __launch_bounds__(1024) void k_select(char* ws) {
    __shared__ u64 sk[4096];
    u32* meta = ws_meta(ws);
    u64* cA = ws_candA(ws);
    u64* cE = ws_candE(ws);
    int tid = threadIdx.x;
    u32 NE = meta[4]; if (NE > 4096u) NE = 4096u;
    u32 NEED = meta[2];
    u32 NG1 = meta[1];
    for (int t = tid; t < 4096; t += 1024) sk[t] = (t < (int)NE) ? cE[t] : 0ull;
    bitonic_desc(sk, 4096);
    for (int t = tid; t < (int)NEED; t += 1024) cA[NG1 + t] = sk[t];
    __syncthreads();
    for (int t = tid; t < K_PRE; t += 1024) sk[t] = cA[t];
    bitonic_desc(sk, K_PRE);
    for (int t = tid; t < K_PRE; t += 1024) cA[t] = sk[t];
}

// ---------------- 5. decode boxes ----------------
__global__ __launch_bounds__(256) void k_decode(const float* __restrict__ bbox, char* ws) {
    int r = blockIdx.x * blockDim.x + threadIdx.x;
    if (r >= K_PRE) return;
    u64 key = ws_candA(ws)[r];
    u32 u = (u32)(key >> 32);
    u32 idx = ~((u32)key);
    if (idx >= NELEM) idx = NELEM - 1;  // safety (pathological pads only)
    u32 bits = (u & 0x80000000u) ? (u ^ 0x80000000u) : ~u;
    float sc = __uint_as_float(bits);
    int b = idx / CHW;
    u32 rem = idx - (u32)b * CHW;
    int c = (int)(rem >> 18);
    u32 rem2 = rem & 0x3FFFFu;
    int h = (int)(rem2 >> 9);
    int w = (int)(rem2 & 511u);
    const float* bp = bbox + (size_t)b * (7 * HWSZ) + rem2;
    float p0 = bp[0 * HWSZ];
    float p1 = bp[1 * HWSZ];
    float p2 = bp[2 * HWSZ];
    float p3 = bp[3 * HWSZ];
    float p4 = bp[4 * HWSZ];
    float p5 = bp[5 * HWSZ];
    float p6 = bp[6 * HWSZ];
    float x = (-51.2f + ((float)w + 0.5f) * 0.2f) + p0;
    float y = (-51.2f + ((float)h + 0.5f) * 0.2f) + p1;
    float bw = expf(p3), bl = expf(p4), bh = expf(p5);
    ws_arr(ws, 0)[r] = sc;
    ws_arr(ws, 1)[r] = x;
    ws_arr(ws, 2)[r] = y;
    ws_arr(ws, 3)[r] = p2;
    ws_arr(ws, 4)[r] = bw;
    ws_arr(ws, 5)[r] = bl;
    ws_arr(ws, 6)[r] = bh;
    ws_arr(ws, 7)[r] = p6;
    float hw = bw * 0.5f, hl = bl * 0.5f;
    ws_arr(ws, 8)[r]  = x - hw;
    ws_arr(ws, 9)[r]  = y - hl;
    ws_arr(ws, 10)[r] = x + hw;
    ws_arr(ws, 11)[r] = y + hl;
    ws_arr(ws, 12)[r] = bw * bl;
    ws_lv(ws)[r] = (u32)c | ((sc > 0.3f) ? 256u : 0u);
}

// ---------------- 6. suppression bit-matrix ----------------
__global__ __launch_bounds__(256) void k_suppmat(char* ws) {
    __shared__ float slox[2048], sloy[2048], shix[2048], shiy[2048], sarea[2048];
    __shared__ u32 slv[2048];
    int tid = threadIdx.x;
    for (int i = tid; i < K_PRE; i += 256) {
        slox[i] = ws_arr(ws, 8)[i];
        sloy[i] = ws_arr(ws, 9)[i];
        shix[i] = ws_arr(ws, 10)[i];
        shiy[i] = ws_arr(ws, 11)[i];
        sarea[i] = ws_arr(ws, 12)[i];
        slv[i] = ws_lv(ws)[i];
    }
    __syncthreads();
    int r = tid >> 5, wj = tid & 31;
    int i = blockIdx.x * 8 + r;
    float lx = slox[i], ly = sloy[i], hx = shix[i], hy = shiy[i], ar = sarea[i];
    u32 li = slv[i] & 0xffu;
    u64 bits = 0;
    for (int s = 0; s < 64; ++s) {
        int off = (s + wj) & 63;       // rotate to avoid LDS bank conflicts
        int j = wj * 64 + off;
        u32 lvj = slv[j];
        bool cnd = (j > i) && ((lvj & 0xffu) == li) && ((lvj >> 8) != 0u);
        if (cnd) {
            float iw = fminf(hx, shix[j]) - fmaxf(lx, slox[j]); iw = fmaxf(iw, 0.0f);
            float ih = fminf(hy, shiy[j]) - fmaxf(ly, sloy[j]); ih = fmaxf(ih, 0.0f);
            float inter = iw * ih;
            float un = (ar + sarea[j] - inter) + 1e-6f;
            cnd = (inter / un) >= 0.5f;
        }
        bits |= ((u64)(cnd ? 1u : 0u)) << off;
    }
    ws_mask(ws)[(size_t)i * 32 + wj] = bits;
}

// ---------------- 7. sequential greedy NMS + emit ----------------
#define NMS_CHUNK 112
#define NMS_NCH 19   // ceil(2048/112)
__global__ __launch_bounds__(1024) void k_nms(char* ws, float* __restrict__ out) {
    u64* mask = ws_mask(ws);
    u32* lv = ws_lv(ws);
    float* score = ws_arr(ws, 0);
    __shared__ u64 rowbuf[2][NMS_CHUNK * 32];
    __shared__ u64 validMask[32];
    __shared__ u64 keepMask[32];
    __shared__ u32 sT;
    int tid = threadIdx.x;
    if (tid < 32) validMask[tid] = 0ull;
    __syncthreads();
    for (int i = tid; i < K_PRE; i += 1024)
        if ((lv[i] >> 8) & 1u) atomicOr(&validMask[i >> 6], 1ull << (i & 63));
    __syncthreads();
    // preload chunk 0
    for (int e = tid; e < NMS_CHUNK * 32; e += 1024) rowbuf[0][e] = mask[e];
    __syncthreads();
    u64 remv = 0ull;
    u64 validLocal = (tid < 64) ? validMask[tid & 31] : 0ull;
    for (int t = 0; t < NMS_NCH; ++t) {
        int base = t * NMS_CHUNK;
        int rows = (base + NMS_CHUNK <= K_PRE) ? NMS_CHUNK : (K_PRE - base);
        if (tid >= 64 && t + 1 < NMS_NCH) {
            int nb = (t + 1) * NMS_CHUNK;
            int nrows = (nb + NMS_CHUNK <= K_PRE) ? NMS_CHUNK : (K_PRE - nb);
            for (int e = tid - 64; e < nrows * 32; e += (1024 - 64))
                rowbuf[(t + 1) & 1][e] = mask[(size_t)nb * 32 + e];
        }
        if (tid < 64) {
            int lane = tid & 31;
            const u64* rb = rowbuf[t & 1];
            for (int ii = 0; ii < rows; ++ii) {
                int i = base + ii;
                u64 aw = shfl_u64(validLocal & ~remv, i >> 6);
                int kp = (int)((aw >> (i & 63)) & 1ull);
                u64 row = rb[ii * 32 + lane];
                if (kp) remv |= row;
            }
        }
        __syncthreads();
    }
    if (tid < 32) keepMask[tid] = validMask[tid] & ~remv;
    __syncthreads();
    if (tid == 0) {
        u32 T = 0;
        for (int w = 0; w < 32; ++w) T += (u32)__popcll(keepMask[w]);
        sT = T;
    }
    __syncthreads();
    u32 T = sT;
    for (int i = tid; i < K_PRE; i += 1024) {
        u64 km = keepMask[i >> 6];
        int bi = i & 63;
        int kp = (int)((km >> bi) & 1ull);
        int rk = 0;
        for (int w = 0; w < (i >> 6); ++w) rk += (int)__popcll(keepMask[w]);
        rk += (int)__popcll(bi ? (km & ((1ull << bi) - 1ull)) : 0ull);
        int slot = -1;
        if (kp) {
            if (rk < MAX_DET) slot = rk;
        } else if ((int)T < MAX_DET) {
            int f = (int)T + (i - rk);
            if (f < MAX_DET) slot = f;
        }
        if (slot >= 0) {
            #pragma unroll
            for (int k = 0; k < 7; ++k)
                out[slot * 8 + k] = kp ? ws_arr(ws, 1 + k)[i] : 0.0f;
            out[slot * 8 + 7] = kp ? score[i] : 0.0f;
            out[8 * MAX_DET + slot] = (float)(lv[i] & 0xffu);
            out[9 * MAX_DET + slot] = kp ? 1.0f : 0.0f;
        }
    }
}

extern "C" void kernel_launch(void* const* d_in, const int* in_sizes, int n_in,
                              void* d_out, int out_size, void* d_ws, size_t ws_size,
                              hipStream_t stream) {
    const float* cls = (const float*)d_in[0];
    const float* bbox = (const float*)d_in[1];
    float* out = (float*)d_out;
    char* ws = (char*)d_ws;
    // zero histogram + meta (counters)
    hipMemsetAsync(ws, 0, NHIST * 4 + 256, stream);
    k_hist<<<128, 512, 0, stream>>>(cls, ws);
    k_scan<<<1, 1024, 0, stream>>>(ws);
    k_compact<<<2560, 256, 0, stream>>>(cls, ws);
    k_select<<<1, 1024, 0, stream>>>(ws);
    k_decode<<<8, 256, 0, stream>>>(bbox, ws);
    k_suppmat<<<256, 256, 0, stream>>>(ws);
    k_nms<<<1, 1024, 0, stream>>>(ws, out);
}

// Round 3
// 313.140 us; speedup vs baseline: 2.5876x; 1.4228x over previous
//
#include <hip/hip_runtime.h>
#include <stdint.h>

typedef unsigned int u32;
typedef unsigned long long u64;

#define K_PRE 2048
#define MAX_DET 100
#define NBATCH 4
#define NCLS 10
#define NH 512
#define NW 512
#define HWSZ (NH*NW)          // 262144 = 2^18
#define CHW (NCLS*HWSZ)       // 2621440
#define NELEM (NBATCH*CHW)    // 10485760
#define NVEC (NELEM/4)
#define NHIST 4096

// ---------------- workspace layout (bytes) ----------------
#define HIST_OFF   0                       // 4096 u32 = 16384 B
#define META_OFF   16384                   // 64 u32
#define CANDA_OFF  16640                   // 2048 u64
#define CANDE_OFF  (CANDA_OFF + 2048*8)    // 4096 u64
#define ARR_BASE   (CANDE_OFF + 4096*8)    // 14 arrays of 2048*4B
#define MASK_OFF   (ARR_BASE + 14*8192)    // 2048*32 u64 = 524288 B (permuted layout)
// total ~705KB

__device__ __forceinline__ u32*  ws_hist(char* ws)  { return (u32*)(ws + HIST_OFF); }
__device__ __forceinline__ u32*  ws_meta(char* ws)  { return (u32*)(ws + META_OFF); }
__device__ __forceinline__ u64*  ws_candA(char* ws) { return (u64*)(ws + CANDA_OFF); }
__device__ __forceinline__ u64*  ws_candE(char* ws) { return (u64*)(ws + CANDE_OFF); }
// arrays: 0=score 1=x 2=y 3=z 4=w 5=l 6=h 7=yaw 8=lox 9=loy 10=hix 11=hiy 12=area
__device__ __forceinline__ float* ws_arr(char* ws, int i) { return (float*)(ws + ARR_BASE + i*8192); }
__device__ __forceinline__ u32*  ws_lv(char* ws)    { return (u32*)(ws + ARR_BASE + 13*8192); }
__device__ __forceinline__ u64*  ws_mask(char* ws)  { return (u64*)(ws + MASK_OFF); }

__device__ __forceinline__ int bucket_of(float v) {
    int b = (int)(v * (float)NHIST);
    b = b < 0 ? 0 : (b > NHIST - 1 ? NHIST - 1 : b);
    return b;
}

__device__ __forceinline__ u64 rdlane64(u64 v, int lane) {
    u32 lo = (u32)__builtin_amdgcn_readlane((int)(u32)v, lane);
    u32 hi = (u32)__builtin_amdgcn_readlane((int)(u32)(v >> 32), lane);
    return ((u64)hi << 32) | lo;
}

__device__ __forceinline__ u64 shflxor32_u64(u64 v) {
    int lo = __shfl_xor((int)(u32)v, 32, 64);
    int hi = __shfl_xor((int)(u32)(v >> 32), 32, 64);
    return ((u64)(u32)hi << 32) | (u32)lo;
}

// ---------------- 1. histogram (LDS-privatized) ----------------
__global__ __launch_bounds__(512) void k_hist(const float* __restrict__ cls, char* ws) {
    __shared__ u32 lh[NHIST];
    int tid = threadIdx.x;
    for (int i = tid; i < NHIST; i += 512) lh[i] = 0u;
    __syncthreads();
    int gid = blockIdx.x * 512 + tid;
    int stride = gridDim.x * 512;
    const float4* cv = (const float4*)cls;
    for (int v = gid; v < NVEC; v += stride) {
        float4 f = cv[v];
        atomicAdd(&lh[bucket_of(f.x)], 1u);
        atomicAdd(&lh[bucket_of(f.y)], 1u);
        atomicAdd(&lh[bucket_of(f.z)], 1u);
        atomicAdd(&lh[bucket_of(f.w)], 1u);
    }
    __syncthreads();
    u32* hist = ws_hist(ws);
    for (int i = tid; i < NHIST; i += 512) {
        u32 c = lh[i];
        if (c) atomicAdd(&hist[i], c);
    }
}

// ---------------- 2. find threshold bucket ----------------
__global__ __launch_bounds__(1024) void k_scan(char* ws) {
    u32* hist = ws_hist(ws);
    u32* meta = ws_meta(ws);
    __shared__ u32 suf[1024];
    __shared__ int sg;
    __shared__ u32 sR;
    int tid = threadIdx.x;
    u32 s = 0;
    int base = tid * 4;
    #pragma unroll
    for (int k = 0; k < 4; ++k) s += hist[base + k];
    suf[tid] = s;
    __syncthreads();
    for (int off = 1; off < 1024; off <<= 1) {
        u32 add = (tid + off < 1024) ? suf[tid + off] : 0u;
        __syncthreads();
        suf[tid] += add;
        __syncthreads();
    }
    bool c0 = suf[tid] >= K_PRE;
    bool c1 = (tid < 1023) ? (suf[tid + 1] >= K_PRE) : false;
    if (c0 && !c1) { sg = tid; sR = (tid < 1023) ? suf[tid + 1] : 0u; }
    __syncthreads();
    if (tid == 0) {
        int g = sg;
        u32 R = sR;
        int B1 = g * 4;
        u32 ng1 = R;
        for (int b = 3; b >= 0; --b) {
            u32 h = hist[g * 4 + b];
            if (R + h >= K_PRE) { B1 = g * 4 + b; ng1 = R; break; }
            R += h;
        }
        meta[0] = (u32)B1;       // threshold bucket
        meta[1] = ng1;           // count strictly above
        meta[2] = K_PRE - ng1;   // NEED from boundary bucket
    }
}

// ---------------- 3. compact candidates ----------------
__global__ __launch_bounds__(256) void k_compact(const float* __restrict__ cls, char* ws) {
    u32* meta = ws_meta(ws);
    u64* cA = ws_candA(ws);
    u64* cE = ws_candE(ws);
    const int B1 = (int)meta[0];
    int gid = blockIdx.x * blockDim.x + threadIdx.x;
    int stride = gridDim.x * blockDim.x;
    const float4* cv = (const float4*)cls;
    for (int v = gid; v < NVEC; v += stride) {
        float4 f = cv[v];
        float vals[4] = {f.x, f.y, f.z, f.w};
        #pragma unroll
        for (int c = 0; c < 4; ++c) {
            int bkt = bucket_of(vals[c]);
            if (bkt >= B1) {
                u32 idx = (u32)(4 * v + c);
                u32 bits = __float_as_uint(vals[c]);
                u32 u = (bits & 0x80000000u) ? ~bits : (bits | 0x80000000u);
                u64 key = ((u64)u << 32) | (u32)(~idx);
                if (bkt > B1) {
                    u32 p = atomicAdd(&meta[3], 1u);
                    if (p < K_PRE) cA[p] = key;
                } else {
                    u32 p = atomicAdd(&meta[4], 1u);
                    if (p < 4096) cE[p] = key;
                }
            }
        }
    }
}

// ---------------- 4. resolve boundary + full sort ----------------
__device__ void bitonic_desc(u64* s, int N) {
    int tid = threadIdx.x;
    for (int k = 2; k <= N; k <<= 1) {
        for (int j = k >> 1; j > 0; j >>= 1) {
            __syncthreads();
            for (int i = tid; i < N; i += blockDim.x) {
                int ixj = i ^ j;
                if (ixj > i) {
                    u64 a = s[i], b = s[ixj];
                    bool sw = ((i & k) == 0) ? (a < b) : (a > b);
                    if (sw) { s[i] = b; s[ixj] = a; }
                }
            }
        }
    }
    __syncthreads();
}

__global__ __launch_bounds__(1024) void k_select(char* ws) {
    __shared__ u64 sk[4096];
    u32* meta = ws_meta(ws);
    u64* cA = ws_candA(ws);
    u64* cE = ws_candE(ws);
    int tid = threadIdx.x;
    u32 NE = meta[4]; if (NE > 4096u) NE = 4096u;
    u32 NEED = meta[2];
    u32 NG1 = meta[1];
    for (int t = tid; t < 4096; t += 1024) sk[t] = (t < (int)NE) ? cE[t] : 0ull;
    bitonic_desc(sk, 4096);
    for (int t = tid; t < (int)NEED; t += 1024) cA[NG1 + t] = sk[t];
    __syncthreads();
    for (int t = tid; t < K_PRE; t += 1024) sk[t] = cA[t];
    bitonic_desc(sk, K_PRE);
    for (int t = tid; t < K_PRE; t += 1024) cA[t] = sk[t];
}

// ---------------- 5. decode boxes ----------------
__global__ __launch_bounds__(256) void k_decode(const float* __restrict__ bbox, char* ws) {
    int r = blockIdx.x * blockDim.x + threadIdx.x;
    if (r >= K_PRE) return;
    u64 key = ws_candA(ws)[r];
    u32 u = (u32)(key >> 32);
    u32 idx = ~((u32)key);
    if (idx >= NELEM) idx = NELEM - 1;  // safety (pathological pads only)
    u32 bits = (u & 0x80000000u) ? (u ^ 0x80000000u) : ~u;
    float sc = __uint_as_float(bits);
    int b = idx / CHW;
    u32 rem = idx - (u32)b * CHW;
    int c = (int)(rem >> 18);
    u32 rem2 = rem & 0x3FFFFu;
    int h = (int)(rem2 >> 9);
    int w = (int)(rem2 & 511u);
    const float* bp = bbox + (size_t)b * (7 * HWSZ) + rem2;
    float p0 = bp[0 * HWSZ];
    float p1 = bp[1 * HWSZ];
    float p2 = bp[2 * HWSZ];
    float p3 = bp[3 * HWSZ];
    float p4 = bp[4 * HWSZ];
    float p5 = bp[5 * HWSZ];
    float p6 = bp[6 * HWSZ];
    float x = (-51.2f + ((float)w + 0.5f) * 0.2f) + p0;
    float y = (-51.2f + ((float)h + 0.5f) * 0.2f) + p1;
    float bw = expf(p3), bl = expf(p4), bh = expf(p5);
    ws_arr(ws, 0)[r] = sc;
    ws_arr(ws, 1)[r] = x;
    ws_arr(ws, 2)[r] = y;
    ws_arr(ws, 3)[r] = p2;
    ws_arr(ws, 4)[r] = bw;
    ws_arr(ws, 5)[r] = bl;
    ws_arr(ws, 6)[r] = bh;
    ws_arr(ws, 7)[r] = p6;
    float hw = bw * 0.5f, hl = bl * 0.5f;
    ws_arr(ws, 8)[r]  = x - hw;
    ws_arr(ws, 9)[r]  = y - hl;
    ws_arr(ws, 10)[r] = x + hw;
    ws_arr(ws, 11)[r] = y + hl;
    ws_arr(ws, 12)[r] = bw * bl;
    ws_lv(ws)[r] = (u32)c | ((sc > 0.3f) ? 256u : 0u);
}

// ---------------- 6. suppression bit-matrix (permuted layout) ----------------
// Element (row i, col-word v) is stored at:
//   W = i>>6, il = i&63
//   g = W*2048 + (il>>2)*128 + ((il&1)*32 + v)*2 + ((il>>1)&1)
// so that in k_nms, lane l's p-th dwordx4 load (offset p*128 + 2*l u64) yields
//   reg[2p+s] = row 2*(2p+s) + (l>>5), col-word l&31.
__global__ __launch_bounds__(256) void k_suppmat(char* ws) {
    __shared__ float slox[2048], sloy[2048], shix[2048], shiy[2048], sarea[2048];
    __shared__ u32 slv[2048];
    int tid = threadIdx.x;
    for (int i = tid; i < K_PRE; i += 256) {
        slox[i] = ws_arr(ws, 8)[i];
        sloy[i] = ws_arr(ws, 9)[i];
        shix[i] = ws_arr(ws, 10)[i];
        shiy[i] = ws_arr(ws, 11)[i];
        sarea[i] = ws_arr(ws, 12)[i];
        slv[i] = ws_lv(ws)[i];
    }
    __syncthreads();
    int r = tid >> 5, wj = tid & 31;
    int i = blockIdx.x * 8 + r;
    float lx = slox[i], ly = sloy[i], hx = shix[i], hy = shiy[i], ar = sarea[i];
    u32 li = slv[i] & 0xffu;
    u64 bits = 0;
    for (int s = 0; s < 64; ++s) {
        int off = (s + wj) & 63;       // rotate to avoid LDS bank conflicts
        int j = wj * 64 + off;
        u32 lvj = slv[j];
        bool cnd = (j > i) && ((lvj & 0xffu) == li) && ((lvj >> 8) != 0u);
        if (cnd) {
            float iw = fminf(hx, shix[j]) - fmaxf(lx, slox[j]); iw = fmaxf(iw, 0.0f);
            float ih = fminf(hy, shiy[j]) - fmaxf(ly, sloy[j]); ih = fmaxf(ih, 0.0f);
            float inter = iw * ih;
            float un = (ar + sarea[j] - inter) + 1e-6f;
            cnd = (inter / un) >= 0.5f;
        }
        bits |= ((u64)(cnd ? 1u : 0u)) << off;
    }
    int W = i >> 6, il = i & 63;
    size_t g = (size_t)W * 2048 + (size_t)((il >> 2) * 128 + ((il & 1) * 32 + wj) * 2 + ((il >> 1) & 1));
    ws_mask(ws)[g] = bits;
}

// ---------------- 7. sequential greedy NMS (single-wave register pipeline) ----------------
__device__ __forceinline__ void nms_load_group(const u64* __restrict__ mask, int W, int lane,
                                               u64 (&buf)[32]) {
    const ulonglong2* gp = (const ulonglong2*)(mask + (size_t)W * 2048);
    #pragma unroll
    for (int p = 0; p < 16; ++p) {
        ulonglong2 t = gp[p * 64 + lane];
        buf[2 * p] = t.x;
        buf[2 * p + 1] = t.y;
    }
}

__device__ __forceinline__ void nms_group(u64 (&cur)[32], u64 (&nxt)[32], int W, int lane,
                                          const u64* __restrict__ mask, u64 valid_dist,
                                          u64& remv_dist) {
    // prefetch next group while computing this one
    nms_load_group(mask, (W + 1) & 31, lane, nxt);
    // ---- intra-block sequential greedy (pure scalar chain) ----
    u64 alive = rdlane64(valid_dist, W) & ~rdlane64(remv_dist, W);
    #pragma unroll
    for (int il = 0; il < 64; ++il) {
        u64 row = rdlane64(cur[il >> 1], ((il & 1) << 5) + W);  // row il, diag col-word W
        u64 sel = (u64)0 - ((alive >> il) & 1ull);
        alive &= ~(row & sel);
    }
    // alive == kept mask for candidates [64W, 64W+64) (uniform)
    // ---- cross-block OR of kept rows (data-parallel) ----
    u64 ksh = alive >> (lane >> 5);   // lanes<32: even rows (bits 2k), lanes>=32: odd rows
    u64 partial = 0;
    #pragma unroll
    for (int k = 0; k < 32; ++k) {
        u64 m = (u64)0 - ((ksh >> (2 * k)) & 1ull);
        partial |= cur[k] & m;
    }
    partial |= shflxor32_u64(partial);   // combine even/odd-row halves
    remv_dist |= partial;                // lane l holds removal word (l&31)
}

__global__ __launch_bounds__(1024) void k_nms(char* ws, float* __restrict__ out) {
    const u64* mask = ws_mask(ws);
    u32* lv = ws_lv(ws);
    float* score = ws_arr(ws, 0);
    __shared__ u64 validMask[32];
    __shared__ u64 keepMask[32];
    __shared__ u32 sT;
    int tid = threadIdx.x;
    if (tid < 32) validMask[tid] = 0ull;
    __syncthreads();
    for (int i = tid; i < K_PRE; i += 1024)
        if ((lv[i] >> 8) & 1u) atomicOr(&validMask[i >> 6], 1ull << (i & 63));
    __syncthreads();

    if (tid < 64) {
        int lane = tid;
        u64 valid_dist = validMask[lane & 31];
        u64 remv_dist = 0ull;
        u64 A[32], B[32];
        nms_load_group(mask, 0, lane, A);
        for (int W = 0; W < 32; W += 2) {
            nms_group(A, B, W, lane, mask, valid_dist, remv_dist);
            nms_group(B, A, W + 1, lane, mask, valid_dist, remv_dist);
        }
        if (lane < 32) keepMask[lane] = valid_dist & ~remv_dist;
    }
    __syncthreads();

    if (tid == 0) {
        u32 T = 0;
        for (int w = 0; w < 32; ++w) T += (u32)__popcll(keepMask[w]);
        sT = T;
    }
    __syncthreads();
    u32 T = sT;
    for (int i = tid; i < K_PRE; i += 1024) {
        u64 km = keepMask[i >> 6];
        int bi = i & 63;
        int kp = (int)((km >> bi) & 1ull);
        int rk = 0;
        for (int w = 0; w < (i >> 6); ++w) rk += (int)__popcll(keepMask[w]);
        rk += (int)__popcll(bi ? (km & ((1ull << bi) - 1ull)) : 0ull);
        int slot = -1;
        if (kp) {
            if (rk < MAX_DET) slot = rk;
        } else if ((int)T < MAX_DET) {
            int f = (int)T + (i - rk);
            if (f < MAX_DET) slot = f;
        }
        if (slot >= 0) {
            #pragma unroll
            for (int k = 0; k < 7; ++k)
                out[slot * 8 + k] = kp ? ws_arr(ws, 1 + k)[i] : 0.0f;
            out[slot * 8 + 7] = kp ? score[i] : 0.0f;
            out[8 * MAX_DET + slot] = (float)(lv[i] & 0xffu);
            out[9 * MAX_DET + slot] = kp ? 1.0f : 0.0f;
        }
    }
}

extern "C" void kernel_launch(void* const* d_in, const int* in_sizes, int n_in,
                              void* d_out, int out_size, void* d_ws, size_t ws_size,
                              hipStream_t stream) {
    const float* cls = (const float*)d_in[0];
    const float* bbox = (const float*)d_in[1];
    float* out = (float*)d_out;
    char* ws = (char*)d_ws;
    // zero histogram + meta (counters)
    hipMemsetAsync(ws, 0, NHIST * 4 + 256, stream);
    k_hist<<<128, 512, 0, stream>>>(cls, ws);
    k_scan<<<1, 1024, 0, stream>>>(ws);
    k_compact<<<2560, 256, 0, stream>>>(cls, ws);
    k_select<<<1, 1024, 0, stream>>>(ws);
    k_decode<<<8, 256, 0, stream>>>(bbox, ws);
    k_suppmat<<<256, 256, 0, stream>>>(ws);
    k_nms<<<1, 1024, 0, stream>>>(ws, out);
}

// Round 4
// 242.843 us; speedup vs baseline: 3.3366x; 1.2895x over previous
//
#include <hip/hip_runtime.h>
#include <stdint.h>

typedef unsigned int u32;
typedef unsigned long long u64;

#define K_PRE 2048
#define MAX_DET 100
#define NBATCH 4
#define NCLS 10
#define NH 512
#define NW 512
#define HWSZ (NH*NW)          // 262144 = 2^18
#define CHW (NCLS*HWSZ)       // 2621440
#define NELEM (NBATCH*CHW)    // 10485760
#define NVEC (NELEM/4)
#define NHIST 4096
#define NCAND 6144            // 2048 above + up to 4096 boundary

// ---------------- workspace layout (bytes) ----------------
#define HIST_OFF   0                       // 4096 u32 = 16384 B
#define META_OFF   16384                   // 64 u32
#define CANDA_OFF  16640                   // 2048 u64
#define CANDE_OFF  (CANDA_OFF + 2048*8)    // 4096 u64
#define CANDS_OFF  (CANDE_OFF + 4096*8)    // 2048 u64 (sorted top-K_PRE)
#define ARR_BASE   (CANDS_OFF + 2048*8)    // 14 arrays of 2048*4B
#define MASK_OFF   (ARR_BASE + 14*8192)    // 2048*32 u64 = 524288 B (permuted layout)
// total ~720KB

__device__ __forceinline__ u32*  ws_hist(char* ws)  { return (u32*)(ws + HIST_OFF); }
__device__ __forceinline__ u32*  ws_meta(char* ws)  { return (u32*)(ws + META_OFF); }
__device__ __forceinline__ u64*  ws_candA(char* ws) { return (u64*)(ws + CANDA_OFF); }
__device__ __forceinline__ u64*  ws_candE(char* ws) { return (u64*)(ws + CANDE_OFF); }
__device__ __forceinline__ u64*  ws_candS(char* ws) { return (u64*)(ws + CANDS_OFF); }
// arrays: 0=score 1=x 2=y 3=z 4=w 5=l 6=h 7=yaw 8=lox 9=loy 10=hix 11=hiy 12=area
__device__ __forceinline__ float* ws_arr(char* ws, int i) { return (float*)(ws + ARR_BASE + i*8192); }
__device__ __forceinline__ u32*  ws_lv(char* ws)    { return (u32*)(ws + ARR_BASE + 13*8192); }
__device__ __forceinline__ u64*  ws_mask(char* ws)  { return (u64*)(ws + MASK_OFF); }

__device__ __forceinline__ int bucket_of(float v) {
    int b = (int)(v * (float)NHIST);
    b = b < 0 ? 0 : (b > NHIST - 1 ? NHIST - 1 : b);
    return b;
}

__device__ __forceinline__ u64 rdlane64(u64 v, int lane) {
    u32 lo = (u32)__builtin_amdgcn_readlane((int)(u32)v, lane);
    u32 hi = (u32)__builtin_amdgcn_readlane((int)(u32)(v >> 32), lane);
    return ((u64)hi << 32) | lo;
}

__device__ __forceinline__ u64 shflxor32_u64(u64 v) {
    int lo = __shfl_xor((int)(u32)v, 32, 64);
    int hi = __shfl_xor((int)(u32)(v >> 32), 32, 64);
    return ((u64)(u32)hi << 32) | (u32)lo;
}

// ---------------- 1. histogram (LDS-privatized) ----------------
__global__ __launch_bounds__(512) void k_hist(const float* __restrict__ cls, char* ws) {
    __shared__ u32 lh[NHIST];
    int tid = threadIdx.x;
    for (int i = tid; i < NHIST; i += 512) lh[i] = 0u;
    __syncthreads();
    int gid = blockIdx.x * 512 + tid;
    int stride = gridDim.x * 512;
    const float4* cv = (const float4*)cls;
    for (int v = gid; v < NVEC; v += stride) {
        float4 f = cv[v];
        atomicAdd(&lh[bucket_of(f.x)], 1u);
        atomicAdd(&lh[bucket_of(f.y)], 1u);
        atomicAdd(&lh[bucket_of(f.z)], 1u);
        atomicAdd(&lh[bucket_of(f.w)], 1u);
    }
    __syncthreads();
    u32* hist = ws_hist(ws);
    for (int i = tid; i < NHIST; i += 512) {
        u32 c = lh[i];
        if (c) atomicAdd(&hist[i], c);
    }
}

// ---------------- 2. find threshold bucket ----------------
__global__ __launch_bounds__(1024) void k_scan(char* ws) {
    u32* hist = ws_hist(ws);
    u32* meta = ws_meta(ws);
    __shared__ u32 suf[1024];
    __shared__ int sg;
    __shared__ u32 sR;
    int tid = threadIdx.x;
    u32 s = 0;
    int base = tid * 4;
    #pragma unroll
    for (int k = 0; k < 4; ++k) s += hist[base + k];
    suf[tid] = s;
    __syncthreads();
    for (int off = 1; off < 1024; off <<= 1) {
        u32 add = (tid + off < 1024) ? suf[tid + off] : 0u;
        __syncthreads();
        suf[tid] += add;
        __syncthreads();
    }
    bool c0 = suf[tid] >= K_PRE;
    bool c1 = (tid < 1023) ? (suf[tid + 1] >= K_PRE) : false;
    if (c0 && !c1) { sg = tid; sR = (tid < 1023) ? suf[tid + 1] : 0u; }
    __syncthreads();
    if (tid == 0) {
        int g = sg;
        u32 R = sR;
        int B1 = g * 4;
        u32 ng1 = R;
        for (int b = 3; b >= 0; --b) {
            u32 h = hist[g * 4 + b];
            if (R + h >= K_PRE) { B1 = g * 4 + b; ng1 = R; break; }
            R += h;
        }
        meta[0] = (u32)B1;       // threshold bucket
        meta[1] = ng1;           // count strictly above
        meta[2] = K_PRE - ng1;   // NEED from boundary bucket
    }
}

// ---------------- 3. compact candidates ----------------
__global__ __launch_bounds__(256) void k_compact(const float* __restrict__ cls, char* ws) {
    u32* meta = ws_meta(ws);
    u64* cA = ws_candA(ws);
    u64* cE = ws_candE(ws);
    const int B1 = (int)meta[0];
    int gid = blockIdx.x * blockDim.x + threadIdx.x;
    int stride = gridDim.x * blockDim.x;
    const float4* cv = (const float4*)cls;
    for (int v = gid; v < NVEC; v += stride) {
        float4 f = cv[v];
        float vals[4] = {f.x, f.y, f.z, f.w};
        #pragma unroll
        for (int c = 0; c < 4; ++c) {
            int bkt = bucket_of(vals[c]);
            if (bkt >= B1) {
                u32 idx = (u32)(4 * v + c);
                u32 bits = __float_as_uint(vals[c]);
                u32 u = (bits & 0x80000000u) ? ~bits : (bits | 0x80000000u);
                u64 key = ((u64)u << 32) | (u32)(~idx);
                if (bkt > B1) {
                    u32 p = atomicAdd(&meta[3], 1u);
                    if (p < K_PRE) cA[p] = key;
                } else {
                    u32 p = atomicAdd(&meta[4], 1u);
                    if (p < 4096) cE[p] = key;
                }
            }
        }
    }
}

// ---------------- 4. rank-based selection sort ----------------
// Keys are distinct => sorted position of key k == #{keys > k}.
// Stage all candidates (above + boundary, zero-padded to NCAND) in LDS,
// 8 threads per row scan interleaved column slices (conflict-free banks),
// scatter to candS[rank] for rank < K_PRE.
__global__ __launch_bounds__(256) void k_rank(char* ws) {
    __shared__ u64 sk[NCAND];   // 48 KiB
    u32* meta = ws_meta(ws);
    int tid = threadIdx.x;
    int NA = (int)meta[3]; if (NA > K_PRE) NA = K_PRE;
    int NE = (int)meta[4]; if (NE > 4096) NE = 4096;
    u64* cA = ws_candA(ws);
    u64* cE = ws_candE(ws);
    for (int j = tid; j < NCAND; j += 256) {
        u64 k = 0ull;
        if (j < NA) k = cA[j];
        else if (j - NA < NE) k = cE[j - NA];
        sk[j] = k;
    }
    __syncthreads();
    int row = blockIdx.x * 32 + (tid >> 3);
    int sub = tid & 7;
    u64 myk = sk[row];
    int cnt = 0;
    #pragma unroll 4
    for (int i = 0; i < NCAND / 8; ++i)
        cnt += (sk[sub + 8 * i] > myk) ? 1 : 0;
    cnt += __shfl_down(cnt, 4, 8);
    cnt += __shfl_down(cnt, 2, 8);
    cnt += __shfl_down(cnt, 1, 8);
    if (sub == 0 && myk != 0ull && cnt < K_PRE)
        ws_candS(ws)[cnt] = myk;
}

// ---------------- 5. decode boxes ----------------
__global__ __launch_bounds__(256) void k_decode(const float* __restrict__ bbox, char* ws) {
    int r = blockIdx.x * blockDim.x + threadIdx.x;
    if (r >= K_PRE) return;
    u64 key = ws_candS(ws)[r];
    u32 u = (u32)(key >> 32);
    u32 idx = ~((u32)key);
    if (idx >= NELEM) idx = NELEM - 1;  // safety (pathological pads only)
    u32 bits = (u & 0x80000000u) ? (u ^ 0x80000000u) : ~u;
    float sc = __uint_as_float(bits);
    int b = idx / CHW;
    u32 rem = idx - (u32)b * CHW;
    int c = (int)(rem >> 18);
    u32 rem2 = rem & 0x3FFFFu;
    int h = (int)(rem2 >> 9);
    int w = (int)(rem2 & 511u);
    const float* bp = bbox + (size_t)b * (7 * HWSZ) + rem2;
    float p0 = bp[0 * HWSZ];
    float p1 = bp[1 * HWSZ];
    float p2 = bp[2 * HWSZ];
    float p3 = bp[3 * HWSZ];
    float p4 = bp[4 * HWSZ];
    float p5 = bp[5 * HWSZ];
    float p6 = bp[6 * HWSZ];
    float x = (-51.2f + ((float)w + 0.5f) * 0.2f) + p0;
    float y = (-51.2f + ((float)h + 0.5f) * 0.2f) + p1;
    float bw = expf(p3), bl = expf(p4), bh = expf(p5);
    ws_arr(ws, 0)[r] = sc;
    ws_arr(ws, 1)[r] = x;
    ws_arr(ws, 2)[r] = y;
    ws_arr(ws, 3)[r] = p2;
    ws_arr(ws, 4)[r] = bw;
    ws_arr(ws, 5)[r] = bl;
    ws_arr(ws, 6)[r] = bh;
    ws_arr(ws, 7)[r] = p6;
    float hw = bw * 0.5f, hl = bl * 0.5f;
    ws_arr(ws, 8)[r]  = x - hw;
    ws_arr(ws, 9)[r]  = y - hl;
    ws_arr(ws, 10)[r] = x + hw;
    ws_arr(ws, 11)[r] = y + hl;
    ws_arr(ws, 12)[r] = bw * bl;
    ws_lv(ws)[r] = (u32)c | ((sc > 0.3f) ? 256u : 0u);
}

// ---------------- 6. suppression bit-matrix (permuted layout) ----------------
// Element (row i, col-word v) is stored at:
//   W = i>>6, il = i&63
//   g = W*2048 + (il>>2)*128 + ((il&1)*32 + v)*2 + ((il>>1)&1)
// so that in k_nms, lane l's p-th dwordx4 load (offset p*128 + 2*l u64) yields
//   reg[2p+s] = row 2*(2p+s) + (l>>5), col-word l&31.
__global__ __launch_bounds__(256) void k_suppmat(char* ws) {
    __shared__ float slox[2048], sloy[2048], shix[2048], shiy[2048], sarea[2048];
    __shared__ u32 slv[2048];
    int tid = threadIdx.x;
    for (int i = tid; i < K_PRE; i += 256) {
        slox[i] = ws_arr(ws, 8)[i];
        sloy[i] = ws_arr(ws, 9)[i];
        shix[i] = ws_arr(ws, 10)[i];
        shiy[i] = ws_arr(ws, 11)[i];
        sarea[i] = ws_arr(ws, 12)[i];
        slv[i] = ws_lv(ws)[i];
    }
    __syncthreads();
    int r = tid >> 5, wj = tid & 31;
    int i = blockIdx.x * 8 + r;
    float lx = slox[i], ly = sloy[i], hx = shix[i], hy = shiy[i], ar = sarea[i];
    u32 li = slv[i] & 0xffu;
    u64 bits = 0;
    for (int s = 0; s < 64; ++s) {
        int off = (s + wj) & 63;       // rotate to avoid LDS bank conflicts
        int j = wj * 64 + off;
        u32 lvj = slv[j];
        bool cnd = (j > i) && ((lvj & 0xffu) == li) && ((lvj >> 8) != 0u);
        if (cnd) {
            float iw = fminf(hx, shix[j]) - fmaxf(lx, slox[j]); iw = fmaxf(iw, 0.0f);
            float ih = fminf(hy, shiy[j]) - fmaxf(ly, sloy[j]); ih = fmaxf(ih, 0.0f);
            float inter = iw * ih;
            float un = (ar + sarea[j] - inter) + 1e-6f;
            cnd = (inter / un) >= 0.5f;
        }
        bits |= ((u64)(cnd ? 1u : 0u)) << off;
    }
    int W = i >> 6, il = i & 63;
    size_t g = (size_t)W * 2048 + (size_t)((il >> 2) * 128 + ((il & 1) * 32 + wj) * 2 + ((il >> 1) & 1));
    ws_mask(ws)[g] = bits;
}

// ---------------- 7. sequential greedy NMS (single-wave register pipeline) ----------------
__device__ __forceinline__ void nms_load_group(const u64* __restrict__ mask, int W, int lane,
                                               u64 (&buf)[32]) {
    const ulonglong2* gp = (const ulonglong2*)(mask + (size_t)W * 2048);
    #pragma unroll
    for (int p = 0; p < 16; ++p) {
        ulonglong2 t = gp[p * 64 + lane];
        buf[2 * p] = t.x;
        buf[2 * p + 1] = t.y;
    }
}

__device__ __forceinline__ void nms_group(u64 (&cur)[32], u64 (&nxt)[32], int W, int lane,
                                          const u64* __restrict__ mask, u64 valid_dist,
                                          u64& remv_dist) {
    // prefetch next group while computing this one
    nms_load_group(mask, (W + 1) & 31, lane, nxt);
    // ---- intra-block sequential greedy (pure scalar chain) ----
    u64 alive = rdlane64(valid_dist, W) & ~rdlane64(remv_dist, W);
    #pragma unroll
    for (int il = 0; il < 64; ++il) {
        u64 row = rdlane64(cur[il >> 1], ((il & 1) << 5) + W);  // row il, diag col-word W
        u64 sel = (u64)0 - ((alive >> il) & 1ull);
        alive &= ~(row & sel);
    }
    // alive == kept mask for candidates [64W, 64W+64) (uniform)
    // ---- cross-block OR of kept rows (data-parallel) ----
    u64 ksh = alive >> (lane >> 5);   // lanes<32: even rows (bits 2k), lanes>=32: odd rows
    u64 partial = 0;
    #pragma unroll
    for (int k = 0; k < 32; ++k) {
        u64 m = (u64)0 - ((ksh >> (2 * k)) & 1ull);
        partial |= cur[k] & m;
    }
    partial |= shflxor32_u64(partial);   // combine even/odd-row halves
    remv_dist |= partial;                // lane l holds removal word (l&31)
}

__global__ __launch_bounds__(1024) void k_nms(char* ws, float* __restrict__ out) {
    const u64* mask = ws_mask(ws);
    u32* lv = ws_lv(ws);
    float* score = ws_arr(ws, 0);
    __shared__ u64 validMask[32];
    __shared__ u64 keepMask[32];
    __shared__ u32 sT;
    int tid = threadIdx.x;
    if (tid < 32) validMask[tid] = 0ull;
    __syncthreads();
    for (int i = tid; i < K_PRE; i += 1024)
        if ((lv[i] >> 8) & 1u) atomicOr(&validMask[i >> 6], 1ull << (i & 63));
    __syncthreads();

    if (tid < 64) {
        int lane = tid;
        u64 valid_dist = validMask[lane & 31];
        u64 remv_dist = 0ull;
        u64 A[32], B[32];
        nms_load_group(mask, 0, lane, A);
        for (int W = 0; W < 32; W += 2) {
            nms_group(A, B, W, lane, mask, valid_dist, remv_dist);
            nms_group(B, A, W + 1, lane, mask, valid_dist, remv_dist);
        }
        if (lane < 32) keepMask[lane] = valid_dist & ~remv_dist;
    }
    __syncthreads();

    if (tid == 0) {
        u32 T = 0;
        for (int w = 0; w < 32; ++w) T += (u32)__popcll(keepMask[w]);
        sT = T;
    }
    __syncthreads();
    u32 T = sT;
    for (int i = tid; i < K_PRE; i += 1024) {
        u64 km = keepMask[i >> 6];
        int bi = i & 63;
        int kp = (int)((km >> bi) & 1ull);
        int rk = 0;
        for (int w = 0; w < (i >> 6); ++w) rk += (int)__popcll(keepMask[w]);
        rk += (int)__popcll(bi ? (km & ((1ull << bi) - 1ull)) : 0ull);
        int slot = -1;
        if (kp) {
            if (rk < MAX_DET) slot = rk;
        } else if ((int)T < MAX_DET) {
            int f = (int)T + (i - rk);
            if (f < MAX_DET) slot = f;
        }
        if (slot >= 0) {
            #pragma unroll
            for (int k = 0; k < 7; ++k)
                out[slot * 8 + k] = kp ? ws_arr(ws, 1 + k)[i] : 0.0f;
            out[slot * 8 + 7] = kp ? score[i] : 0.0f;
            out[8 * MAX_DET + slot] = (float)(lv[i] & 0xffu);
            out[9 * MAX_DET + slot] = kp ? 1.0f : 0.0f;
        }
    }
}

extern "C" void kernel_launch(void* const* d_in, const int* in_sizes, int n_in,
                              void* d_out, int out_size, void* d_ws, size_t ws_size,
                              hipStream_t stream) {
    const float* cls = (const float*)d_in[0];
    const float* bbox = (const float*)d_in[1];
    float* out = (float*)d_out;
    char* ws = (char*)d_ws;
    // zero histogram + meta (counters)
    hipMemsetAsync(ws, 0, NHIST * 4 + 256, stream);
    k_hist<<<256, 512, 0, stream>>>(cls, ws);
    k_scan<<<1, 1024, 0, stream>>>(ws);
    k_compact<<<2560, 256, 0, stream>>>(cls, ws);
    k_rank<<<NCAND / 32, 256, 0, stream>>>(ws);
    k_decode<<<8, 256, 0, stream>>>(bbox, ws);
    k_suppmat<<<256, 256, 0, stream>>>(ws);
    k_nms<<<1, 1024, 0, stream>>>(ws, out);
}

// Round 5
// 210.216 us; speedup vs baseline: 3.8545x; 1.1552x over previous
//
#include <hip/hip_runtime.h>
#include <stdint.h>

typedef unsigned int u32;
typedef unsigned long long u64;

#define K_PRE 2048
#define MAX_DET 100
#define NBATCH 4
#define NCLS 10
#define NH 512
#define NW 512
#define HWSZ (NH*NW)          // 262144 = 2^18
#define CHW (NCLS*HWSZ)       // 2621440
#define NELEM (NBATCH*CHW)    // 10485760
#define NVEC (NELEM/4)
#define NHIST 4096
#define NCAND 6144            // 2048 above + up to 4096 boundary

// ---------------- workspace layout (bytes) ----------------
#define HIST_OFF   0                       // 4096 u32 = 16384 B
#define META_OFF   16384                   // 64 u32
#define CANDA_OFF  16640                   // 2048 u64
#define CANDE_OFF  (CANDA_OFF + 2048*8)    // 4096 u64
#define CANDS_OFF  (CANDE_OFF + 4096*8)    // 2048 u64 (sorted top-K_PRE)
#define ARR_BASE   (CANDS_OFF + 2048*8)    // 14 arrays of 2048*4B
#define MASK_OFF   (ARR_BASE + 14*8192)    // 2048*32 u64 = 524288 B (permuted layout)
#define DIAGT_OFF  (MASK_OFF + 2048*32*8)  // 2048 u64 transposed diag words
// total ~738KB

__device__ __forceinline__ u32*  ws_hist(char* ws)  { return (u32*)(ws + HIST_OFF); }
__device__ __forceinline__ u32*  ws_meta(char* ws)  { return (u32*)(ws + META_OFF); }
__device__ __forceinline__ u64*  ws_candA(char* ws) { return (u64*)(ws + CANDA_OFF); }
__device__ __forceinline__ u64*  ws_candE(char* ws) { return (u64*)(ws + CANDE_OFF); }
__device__ __forceinline__ u64*  ws_candS(char* ws) { return (u64*)(ws + CANDS_OFF); }
// arrays: 0=score 1=x 2=y 3=z 4=w 5=l 6=h 7=yaw 8=lox 9=loy 10=hix 11=hiy 12=area
__device__ __forceinline__ float* ws_arr(char* ws, int i) { return (float*)(ws + ARR_BASE + i*8192); }
__device__ __forceinline__ u32*  ws_lv(char* ws)    { return (u32*)(ws + ARR_BASE + 13*8192); }
__device__ __forceinline__ u64*  ws_mask(char* ws)  { return (u64*)(ws + MASK_OFF); }
__device__ __forceinline__ u64*  ws_diagT(char* ws) { return (u64*)(ws + DIAGT_OFF); }

__device__ __forceinline__ int bucket_of(float v) {
    int b = (int)(v * (float)NHIST);
    b = b < 0 ? 0 : (b > NHIST - 1 ? NHIST - 1 : b);
    return b;
}

__device__ __forceinline__ u64 rdlane64(u64 v, int lane) {
    u32 lo = (u32)__builtin_amdgcn_readlane((int)(u32)v, lane);
    u32 hi = (u32)__builtin_amdgcn_readlane((int)(u32)(v >> 32), lane);
    return ((u64)hi << 32) | lo;
}

__device__ __forceinline__ u64 shflxor32_u64(u64 v) {
    int lo = __shfl_xor((int)(u32)v, 32, 64);
    int hi = __shfl_xor((int)(u32)(v >> 32), 32, 64);
    return ((u64)(u32)hi << 32) | (u32)lo;
}

// ---------------- 1. histogram (LDS-privatized) ----------------
__global__ __launch_bounds__(512) void k_hist(const float* __restrict__ cls, char* ws) {
    __shared__ u32 lh[NHIST];
    int tid = threadIdx.x;
    for (int i = tid; i < NHIST; i += 512) lh[i] = 0u;
    __syncthreads();
    int gid = blockIdx.x * 512 + tid;
    int stride = gridDim.x * 512;
    const float4* cv = (const float4*)cls;
    for (int v = gid; v < NVEC; v += stride) {
        float4 f = cv[v];
        atomicAdd(&lh[bucket_of(f.x)], 1u);
        atomicAdd(&lh[bucket_of(f.y)], 1u);
        atomicAdd(&lh[bucket_of(f.z)], 1u);
        atomicAdd(&lh[bucket_of(f.w)], 1u);
    }
    __syncthreads();
    u32* hist = ws_hist(ws);
    for (int i = tid; i < NHIST; i += 512) {
        u32 c = lh[i];
        if (c) atomicAdd(&hist[i], c);
    }
}

// ---------------- 2. find threshold bucket ----------------
__global__ __launch_bounds__(1024) void k_scan(char* ws) {
    u32* hist = ws_hist(ws);
    u32* meta = ws_meta(ws);
    __shared__ u32 suf[1024];
    __shared__ int sg;
    __shared__ u32 sR;
    int tid = threadIdx.x;
    u32 s = 0;
    int base = tid * 4;
    #pragma unroll
    for (int k = 0; k < 4; ++k) s += hist[base + k];
    suf[tid] = s;
    __syncthreads();
    for (int off = 1; off < 1024; off <<= 1) {
        u32 add = (tid + off < 1024) ? suf[tid + off] : 0u;
        __syncthreads();
        suf[tid] += add;
        __syncthreads();
    }
    bool c0 = suf[tid] >= K_PRE;
    bool c1 = (tid < 1023) ? (suf[tid + 1] >= K_PRE) : false;
    if (c0 && !c1) { sg = tid; sR = (tid < 1023) ? suf[tid + 1] : 0u; }
    __syncthreads();
    if (tid == 0) {
        int g = sg;
        u32 R = sR;
        int B1 = g * 4;
        u32 ng1 = R;
        for (int b = 3; b >= 0; --b) {
            u32 h = hist[g * 4 + b];
            if (R + h >= K_PRE) { B1 = g * 4 + b; ng1 = R; break; }
            R += h;
        }
        meta[0] = (u32)B1;       // threshold bucket
        meta[1] = ng1;           // count strictly above
        meta[2] = K_PRE - ng1;   // NEED from boundary bucket
    }
}

// ---------------- 3. compact candidates ----------------
__global__ __launch_bounds__(256) void k_compact(const float* __restrict__ cls, char* ws) {
    u32* meta = ws_meta(ws);
    u64* cA = ws_candA(ws);
    u64* cE = ws_candE(ws);
    const int B1 = (int)meta[0];
    int gid = blockIdx.x * blockDim.x + threadIdx.x;
    int stride = gridDim.x * blockDim.x;
    const float4* cv = (const float4*)cls;
    for (int v = gid; v < NVEC; v += stride) {
        float4 f = cv[v];
        float vals[4] = {f.x, f.y, f.z, f.w};
        #pragma unroll
        for (int c = 0; c < 4; ++c) {
            int bkt = bucket_of(vals[c]);
            if (bkt >= B1) {
                u32 idx = (u32)(4 * v + c);
                u32 bits = __float_as_uint(vals[c]);
                u32 u = (bits & 0x80000000u) ? ~bits : (bits | 0x80000000u);
                u64 key = ((u64)u << 32) | (u32)(~idx);
                if (bkt > B1) {
                    u32 p = atomicAdd(&meta[3], 1u);
                    if (p < K_PRE) cA[p] = key;
                } else {
                    u32 p = atomicAdd(&meta[4], 1u);
                    if (p < 4096) cE[p] = key;
                }
            }
        }
    }
}

// ---------------- 4. rank-based selection sort ----------------
__global__ __launch_bounds__(256) void k_rank(char* ws) {
    __shared__ u64 sk[NCAND];   // 48 KiB
    u32* meta = ws_meta(ws);
    int tid = threadIdx.x;
    int NA = (int)meta[3]; if (NA > K_PRE) NA = K_PRE;
    int NE = (int)meta[4]; if (NE > 4096) NE = 4096;
    u64* cA = ws_candA(ws);
    u64* cE = ws_candE(ws);
    for (int j = tid; j < NCAND; j += 256) {
        u64 k = 0ull;
        if (j < NA) k = cA[j];
        else if (j - NA < NE) k = cE[j - NA];
        sk[j] = k;
    }
    __syncthreads();
    int row = blockIdx.x * 32 + (tid >> 3);
    int sub = tid & 7;
    u64 myk = sk[row];
    int cnt = 0;
    #pragma unroll 4
    for (int i = 0; i < NCAND / 8; ++i)
        cnt += (sk[sub + 8 * i] > myk) ? 1 : 0;
    cnt += __shfl_down(cnt, 4, 8);
    cnt += __shfl_down(cnt, 2, 8);
    cnt += __shfl_down(cnt, 1, 8);
    if (sub == 0 && myk != 0ull && cnt < K_PRE)
        ws_candS(ws)[cnt] = myk;
}

// ---------------- 5. decode boxes ----------------
__global__ __launch_bounds__(256) void k_decode(const float* __restrict__ bbox, char* ws) {
    int r = blockIdx.x * blockDim.x + threadIdx.x;
    if (r >= K_PRE) return;
    u64 key = ws_candS(ws)[r];
    u32 u = (u32)(key >> 32);
    u32 idx = ~((u32)key);
    if (idx >= NELEM) idx = NELEM - 1;  // safety
    u32 bits = (u & 0x80000000u) ? (u ^ 0x80000000u) : ~u;
    float sc = __uint_as_float(bits);
    int b = idx / CHW;
    u32 rem = idx - (u32)b * CHW;
    int c = (int)(rem >> 18);
    u32 rem2 = rem & 0x3FFFFu;
    int h = (int)(rem2 >> 9);
    int w = (int)(rem2 & 511u);
    const float* bp = bbox + (size_t)b * (7 * HWSZ) + rem2;
    float p0 = bp[0 * HWSZ];
    float p1 = bp[1 * HWSZ];
    float p2 = bp[2 * HWSZ];
    float p3 = bp[3 * HWSZ];
    float p4 = bp[4 * HWSZ];
    float p5 = bp[5 * HWSZ];
    float p6 = bp[6 * HWSZ];
    float x = (-51.2f + ((float)w + 0.5f) * 0.2f) + p0;
    float y = (-51.2f + ((float)h + 0.5f) * 0.2f) + p1;
    float bw = expf(p3), bl = expf(p4), bh = expf(p5);
    ws_arr(ws, 0)[r] = sc;
    ws_arr(ws, 1)[r] = x;
    ws_arr(ws, 2)[r] = y;
    ws_arr(ws, 3)[r] = p2;
    ws_arr(ws, 4)[r] = bw;
    ws_arr(ws, 5)[r] = bl;
    ws_arr(ws, 6)[r] = bh;
    ws_arr(ws, 7)[r] = p6;
    float hw = bw * 0.5f, hl = bl * 0.5f;
    ws_arr(ws, 8)[r]  = x - hw;
    ws_arr(ws, 9)[r]  = y - hl;
    ws_arr(ws, 10)[r] = x + hw;
    ws_arr(ws, 11)[r] = y + hl;
    ws_arr(ws, 12)[r] = bw * bl;
    ws_lv(ws)[r] = (u32)c | ((sc > 0.3f) ? 256u : 0u);
}

// ---------------- 6. suppression bit-matrix (permuted) + transposed diag ----------------
// Row-word layout (for k_nms register tiling), unchanged from prior round:
//   W = i>>6, il = i&63
//   g = W*2048 + (il>>2)*128 + ((il&1)*32 + wj)*2 + ((il>>1)&1)
// Additional: diagT[i] = sym-IoU bits of row i restricted to cols j<i of i's own
// 64-block, ANDed with valid[i] (column validity). Used by k_nms's Jacobi step.
__global__ __launch_bounds__(256) void k_suppmat(char* ws) {
    __shared__ float slox[2048], sloy[2048], shix[2048], shiy[2048], sarea[2048];
    __shared__ u32 slv[2048];
    int tid = threadIdx.x;
    for (int i = tid; i < K_PRE; i += 256) {
        slox[i] = ws_arr(ws, 8)[i];
        sloy[i] = ws_arr(ws, 9)[i];
        shix[i] = ws_arr(ws, 10)[i];
        shiy[i] = ws_arr(ws, 11)[i];
        sarea[i] = ws_arr(ws, 12)[i];
        slv[i] = ws_lv(ws)[i];
    }
    __syncthreads();
    int r = tid >> 5, wj = tid & 31;
    int i = blockIdx.x * 8 + r;
    bool diagw = (wj == (i >> 6));
    float lx = slox[i], ly = sloy[i], hx = shix[i], hy = shiy[i], ar = sarea[i];
    u32 li = slv[i] & 0xffu;
    u64 bits = 0, sym = 0;
    for (int s = 0; s < 64; ++s) {
        int off = (s + wj) & 63;       // rotate to avoid LDS bank conflicts
        int j = wj * 64 + off;
        u32 lvj = slv[j];
        bool same = ((lvj & 0xffu) == li) && (j != i);
        bool fwd = same && (j > i) && ((lvj >> 8) != 0u);
        bool bwd = diagw && same && (j < i);
        bool io = false;
        if (fwd || bwd) {
            float iw = fminf(hx, shix[j]) - fmaxf(lx, slox[j]); iw = fmaxf(iw, 0.0f);
            float ih = fminf(hy, shiy[j]) - fmaxf(ly, sloy[j]); ih = fmaxf(ih, 0.0f);
            float inter = iw * ih;
            float un = (ar + sarea[j] - inter) + 1e-6f;
            io = (inter / un) >= 0.5f;
        }
        bits |= ((u64)((io && fwd) ? 1u : 0u)) << off;
        sym  |= ((u64)((io && bwd) ? 1u : 0u)) << off;
    }
    int W = i >> 6, il = i & 63;
    size_t g = (size_t)W * 2048 + (size_t)((il >> 2) * 128 + ((il & 1) * 32 + wj) * 2 + ((il >> 1) & 1));
    ws_mask(ws)[g] = bits;
    if (diagw) {
        u64 dt = sym;                      // bwd already restricts to j<i
        if (!((slv[i] >> 8) & 1u)) dt = 0; // fold column validity
        ws_diagT(ws)[i] = dt;
    }
}

// ---------------- 7. greedy NMS: Jacobi diag + register cross-block OR ----------------
__device__ __forceinline__ void nms_load_group(const u64* __restrict__ mask, int W, int lane,
                                               u64 (&buf)[32]) {
    const ulonglong2* gp = (const ulonglong2*)(mask + (size_t)W * 2048);
    #pragma unroll
    for (int p = 0; p < 16; ++p) {
        ulonglong2 t = gp[p * 64 + lane];
        buf[2 * p] = t.x;
        buf[2 * p + 1] = t.y;
    }
}

__device__ __forceinline__ void nms_block(u64 (&cur)[32], u64 (&nxt)[32],
                                          u64 dtw, u64& dtw_n,
                                          int W, int lane,
                                          const u64* __restrict__ mask,
                                          const u64* __restrict__ diagT,
                                          u64 valid_dist, u64& remv_dist) {
    if (W + 1 < 32) {
        nms_load_group(mask, W + 1, lane, nxt);      // prefetch next block
        dtw_n = diagT[(W + 1) * 64 + lane];
    }
    u64 av0 = rdlane64(valid_dist, W) & ~rdlane64(remv_dist, W);
    // Jacobi fixed-point on the triangular diag system; unique FP == greedy.
    u64 a = av0;
    #pragma unroll 1
    for (int it = 0; it < 66; ++it) {
        bool self = ((av0 >> lane) & 1ull) != 0ull;
        bool rem = (dtw & a) != 0ull;
        u64 na = __ballot(self && !rem);
        if (na == a) break;
        a = na;
    }
    // cross-block OR of kept rows (a is uniform)
    u64 ksh = a >> (lane >> 5);   // lanes<32: even rows, lanes>=32: odd rows
    u64 partial = 0;
    #pragma unroll
    for (int k = 0; k < 32; ++k) {
        u64 m = (u64)0 - ((ksh >> (2 * k)) & 1ull);
        partial |= cur[k] & m;
    }
    partial |= shflxor32_u64(partial);   // combine even/odd halves
    remv_dist |= partial;                // lane l holds removal word (l&31)
}

__global__ __launch_bounds__(256, 1) void k_nms(char* ws, float* __restrict__ out) {
    const u64* mask = ws_mask(ws);
    const u64* diagT = ws_diagT(ws);
    u32* lv = ws_lv(ws);
    float* score = ws_arr(ws, 0);
    __shared__ u64 validMask[32];
    __shared__ u64 keepMask[32];
    __shared__ u32 sT;
    int tid = threadIdx.x;
    if (tid < 32) validMask[tid] = 0ull;
    __syncthreads();
    for (int i = tid; i < K_PRE; i += 256)
        if ((lv[i] >> 8) & 1u) atomicOr(&validMask[i >> 6], 1ull << (i & 63));
    __syncthreads();

    if (tid < 64) {
        int lane = tid;
        u64 valid_dist = validMask[lane & 31];
        u64 remv_dist = 0ull;
        u64 A[32], B[32];
        u64 dt0, dt1;
        nms_load_group(mask, 0, lane, A);
        dt0 = diagT[lane];
        for (int W = 0; W < 32; W += 2) {
            nms_block(A, B, dt0, dt1, W, lane, mask, diagT, valid_dist, remv_dist);
            nms_block(B, A, dt1, dt0, W + 1, lane, mask, diagT, valid_dist, remv_dist);
        }
        if (lane < 32) keepMask[lane] = valid_dist & ~remv_dist;
    }
    __syncthreads();

    if (tid == 0) {
        u32 T = 0;
        for (int w = 0; w < 32; ++w) T += (u32)__popcll(keepMask[w]);
        sT = T;
    }
    __syncthreads();
    u32 T = sT;
    for (int i = tid; i < K_PRE; i += 256) {
        u64 km = keepMask[i >> 6];
        int bi = i & 63;
        int kp = (int)((km >> bi) & 1ull);
        int rk = 0;
        for (int w = 0; w < (i >> 6); ++w) rk += (int)__popcll(keepMask[w]);
        rk += (int)__popcll(bi ? (km & ((1ull << bi) - 1ull)) : 0ull);
        int slot = -1;
        if (kp) {
            if (rk < MAX_DET) slot = rk;
        } else if ((int)T < MAX_DET) {
            int f = (int)T + (i - rk);
            if (f < MAX_DET) slot = f;
        }
        if (slot >= 0) {
            #pragma unroll
            for (int k = 0; k < 7; ++k)
                out[slot * 8 + k] = kp ? ws_arr(ws, 1 + k)[i] : 0.0f;
            out[slot * 8 + 7] = kp ? score[i] : 0.0f;
            out[8 * MAX_DET + slot] = (float)(lv[i] & 0xffu);
            out[9 * MAX_DET + slot] = kp ? 1.0f : 0.0f;
        }
    }
}

extern "C" void kernel_launch(void* const* d_in, const int* in_sizes, int n_in,
                              void* d_out, int out_size, void* d_ws, size_t ws_size,
                              hipStream_t stream) {
    const float* cls = (const float*)d_in[0];
    const float* bbox = (const float*)d_in[1];
    float* out = (float*)d_out;
    char* ws = (char*)d_ws;
    // zero histogram + meta (counters)
    hipMemsetAsync(ws, 0, NHIST * 4 + 256, stream);
    k_hist<<<256, 512, 0, stream>>>(cls, ws);
    k_scan<<<1, 1024, 0, stream>>>(ws);
    k_compact<<<2560, 256, 0, stream>>>(cls, ws);
    k_rank<<<NCAND / 32, 256, 0, stream>>>(ws);
    k_decode<<<8, 256, 0, stream>>>(bbox, ws);
    k_suppmat<<<256, 256, 0, stream>>>(ws);
    k_nms<<<1, 256, 0, stream>>>(ws, out);
}

// Round 6
// 208.914 us; speedup vs baseline: 3.8785x; 1.0062x over previous
//
#include <hip/hip_runtime.h>
#include <stdint.h>

typedef unsigned int u32;
typedef unsigned long long u64;

#define K_PRE 2048
#define MAX_DET 100
#define NBATCH 4
#define NCLS 10
#define NH 512
#define NW 512
#define HWSZ (NH*NW)          // 262144 = 2^18
#define CHW (NCLS*HWSZ)       // 2621440
#define NELEM (NBATCH*CHW)    // 10485760
#define NVEC (NELEM/4)        // 2621440 float4
#define NCHUNK (NVEC/64)      // 40960 chunks of 256 elements
#define NHIST 4096
#define NCAND 6144            // 2048 above + up to 4096 boundary

// ---------------- workspace layout (bytes) ----------------
#define HIST_OFF   0                       // 4096 u32 = 16384 B
#define META_OFF   16384                   // 64 u32
#define CANDA_OFF  16640                   // 2048 u64
#define CANDE_OFF  (CANDA_OFF + 2048*8)    // 4096 u64
#define ARR_BASE   (CANDE_OFF + 4096*8)    // 14 arrays of 2048*4B
#define MASK_OFF   (ARR_BASE + 14*8192)    // 2048*32 u64 = 524288 B (permuted layout)
#define DIAGT_OFF  (MASK_OFF + 2048*32*8)  // 2048 u64 transposed diag words
#define CMAX_OFF   (DIAGT_OFF + 2048*8)    // 40960 f32 chunk maxima = 163840 B
// total ~1.0 MB

__device__ __forceinline__ u32*  ws_hist(char* ws)  { return (u32*)(ws + HIST_OFF); }
__device__ __forceinline__ u32*  ws_meta(char* ws)  { return (u32*)(ws + META_OFF); }
__device__ __forceinline__ u64*  ws_candA(char* ws) { return (u64*)(ws + CANDA_OFF); }
__device__ __forceinline__ u64*  ws_candE(char* ws) { return (u64*)(ws + CANDE_OFF); }
// arrays: 0=score 1=x 2=y 3=z 4=w 5=l 6=h 7=yaw 8=lox 9=loy 10=hix 11=hiy 12=area
__device__ __forceinline__ float* ws_arr(char* ws, int i) { return (float*)(ws + ARR_BASE + i*8192); }
__device__ __forceinline__ u32*  ws_lv(char* ws)    { return (u32*)(ws + ARR_BASE + 13*8192); }
__device__ __forceinline__ u64*  ws_mask(char* ws)  { return (u64*)(ws + MASK_OFF); }
__device__ __forceinline__ u64*  ws_diagT(char* ws) { return (u64*)(ws + DIAGT_OFF); }
__device__ __forceinline__ float* ws_cmax(char* ws) { return (float*)(ws + CMAX_OFF); }

__device__ __forceinline__ int bucket_of(float v) {
    int b = (int)(v * (float)NHIST);
    b = b < 0 ? 0 : (b > NHIST - 1 ? NHIST - 1 : b);
    return b;
}

__device__ __forceinline__ u64 rdlane64(u64 v, int lane) {
    u32 lo = (u32)__builtin_amdgcn_readlane((int)(u32)v, lane);
    u32 hi = (u32)__builtin_amdgcn_readlane((int)(u32)(v >> 32), lane);
    return ((u64)hi << 32) | lo;
}

__device__ __forceinline__ u64 shflxor32_u64(u64 v) {
    int lo = __shfl_xor((int)(u32)v, 32, 64);
    int hi = __shfl_xor((int)(u32)(v >> 32), 32, 64);
    return ((u64)(u32)hi << 32) | (u32)lo;
}

// ---------------- 1. histogram (LDS-privatized) + chunk maxima ----------------
__global__ __launch_bounds__(512) void k_hist(const float* __restrict__ cls, char* ws) {
    __shared__ u32 lh[NHIST];
    int tid = threadIdx.x;
    for (int i = tid; i < NHIST; i += 512) lh[i] = 0u;
    __syncthreads();
    int gid = blockIdx.x * 512 + tid;
    int stride = gridDim.x * 512;
    int lane = tid & 63;
    float* cmax = ws_cmax(ws);
    const float4* cv = (const float4*)cls;
    for (int v = gid; v < NVEC; v += stride) {
        float4 f = cv[v];
        atomicAdd(&lh[bucket_of(f.x)], 1u);
        atomicAdd(&lh[bucket_of(f.y)], 1u);
        atomicAdd(&lh[bucket_of(f.z)], 1u);
        atomicAdd(&lh[bucket_of(f.w)], 1u);
        float m = fmaxf(fmaxf(f.x, f.y), fmaxf(f.z, f.w));
        #pragma unroll
        for (int off = 1; off < 64; off <<= 1)
            m = fmaxf(m, __shfl_xor(m, off, 64));
        if (lane == 0) cmax[v >> 6] = m;   // v>>6 uniform per wave (base %64==0)
    }
    __syncthreads();
    u32* hist = ws_hist(ws);
    for (int i = tid; i < NHIST; i += 512) {
        u32 c = lh[i];
        if (c) atomicAdd(&hist[i], c);
    }
}

// ---------------- 2. compact candidates (chunk-max guided, block-local scan) ----------------
__global__ __launch_bounds__(256) void k_compact(const float* __restrict__ cls, char* ws) {
    __shared__ u32 part[256];
    __shared__ int sB1;
    u32* hist = ws_hist(ws);
    u32* meta = ws_meta(ws);
    u64* cA = ws_candA(ws);
    u64* cE = ws_candE(ws);
    int tid = threadIdx.x;
    // Phase A: redundant threshold-bucket scan (identical in every block)
    u32 s = 0;
    int base = tid * 16;
    #pragma unroll
    for (int k = 0; k < 16; ++k) s += hist[base + k];
    part[tid] = s;
    __syncthreads();
    for (int off = 1; off < 256; off <<= 1) {
        u32 add = (tid + off < 256) ? part[tid + off] : 0u;
        __syncthreads();
        part[tid] += add;
        __syncthreads();
    }
    bool c0 = part[tid] >= K_PRE;
    bool c1 = (tid < 255) ? (part[tid + 1] >= K_PRE) : false;
    if (c0 && !c1) {
        u32 R = (tid < 255) ? part[tid + 1] : 0u;
        int B1 = tid * 16;
        for (int b = 15; b >= 0; --b) {
            u32 h = hist[tid * 16 + b];
            if (R + h >= K_PRE) { B1 = tid * 16 + b; break; }
            R += h;
        }
        sB1 = B1;
    }
    __syncthreads();
    const int B1 = sB1;
    // Phase B: scan chunk maxima, process only candidate-bearing chunks
    int wave = tid >> 6, lane = tid & 63;
    int wbase = (blockIdx.x * 4 + wave) * 64;   // 64 chunks per wave
    const float* cmax = ws_cmax(ws);
    const float4* cv = (const float4*)cls;
    float cm = cmax[wbase + lane];
    u64 ball = __ballot(bucket_of(cm) >= B1);
    while (ball) {
        int b = __ffsll((unsigned long long)ball) - 1;
        ball &= ball - 1;
        int cc = wbase + b;
        int v = cc * 64 + lane;
        float4 f = cv[v];
        float vals[4] = {f.x, f.y, f.z, f.w};
        #pragma unroll
        for (int c = 0; c < 4; ++c) {
            int bkt = bucket_of(vals[c]);
            if (bkt >= B1) {
                u32 idx = (u32)(4 * v + c);
                u32 bits = __float_as_uint(vals[c]);
                u32 u = (bits & 0x80000000u) ? ~bits : (bits | 0x80000000u);
                u64 key = ((u64)u << 32) | (u32)(~idx);
                if (bkt > B1) {
                    u32 p = atomicAdd(&meta[3], 1u);
                    if (p < K_PRE) cA[p] = key;
                } else {
                    u32 p = atomicAdd(&meta[4], 1u);
                    if (p < 4096) cE[p] = key;
                }
            }
        }
    }
}

// ---------------- 3. rank-based selection + fused decode ----------------
// Keys distinct => sorted position == #{keys > k}. 8 threads per row scan
// interleaved column slices; the sub==0 thread decodes its box directly
// into arrays[rank] when rank < K_PRE.
__global__ __launch_bounds__(256) void k_rankdec(const float* __restrict__ bbox, char* ws) {
    __shared__ u64 sk[NCAND];   // 48 KiB
    u32* meta = ws_meta(ws);
    int tid = threadIdx.x;
    int NA = (int)meta[3]; if (NA > K_PRE) NA = K_PRE;
    int NE = (int)meta[4]; if (NE > 4096) NE = 4096;
    u64* cA = ws_candA(ws);
    u64* cE = ws_candE(ws);
    for (int j = tid; j < NCAND; j += 256) {
        u64 k = 0ull;
        if (j < NA) k = cA[j];
        else if (j - NA < NE) k = cE[j - NA];
        sk[j] = k;
    }
    __syncthreads();
    int row = blockIdx.x * 32 + (tid >> 3);
    int sub = tid & 7;
    u64 myk = sk[row];
    int cnt = 0;
    #pragma unroll 4
    for (int i = 0; i < NCAND / 8; ++i)
        cnt += (sk[sub + 8 * i] > myk) ? 1 : 0;
    cnt += __shfl_down(cnt, 4, 8);
    cnt += __shfl_down(cnt, 2, 8);
    cnt += __shfl_down(cnt, 1, 8);
    if (sub == 0 && myk != 0ull && cnt < K_PRE) {
        int r = cnt;
        u32 u = (u32)(myk >> 32);
        u32 idx = ~((u32)myk);
        if (idx >= NELEM) idx = NELEM - 1;
        u32 bits = (u & 0x80000000u) ? (u ^ 0x80000000u) : ~u;
        float sc = __uint_as_float(bits);
        int b = idx / CHW;
        u32 rem = idx - (u32)b * CHW;
        int c = (int)(rem >> 18);
        u32 rem2 = rem & 0x3FFFFu;
        int h = (int)(rem2 >> 9);
        int w = (int)(rem2 & 511u);
        const float* bp = bbox + (size_t)b * (7 * HWSZ) + rem2;
        float p0 = bp[0 * HWSZ];
        float p1 = bp[1 * HWSZ];
        float p2 = bp[2 * HWSZ];
        float p3 = bp[3 * HWSZ];
        float p4 = bp[4 * HWSZ];
        float p5 = bp[5 * HWSZ];
        float p6 = bp[6 * HWSZ];
        float x = (-51.2f + ((float)w + 0.5f) * 0.2f) + p0;
        float y = (-51.2f + ((float)h + 0.5f) * 0.2f) + p1;
        float bw = expf(p3), bl = expf(p4), bh = expf(p5);
        ws_arr(ws, 0)[r] = sc;
        ws_arr(ws, 1)[r] = x;
        ws_arr(ws, 2)[r] = y;
        ws_arr(ws, 3)[r] = p2;
        ws_arr(ws, 4)[r] = bw;
        ws_arr(ws, 5)[r] = bl;
        ws_arr(ws, 6)[r] = bh;
        ws_arr(ws, 7)[r] = p6;
        float hw = bw * 0.5f, hl = bl * 0.5f;
        ws_arr(ws, 8)[r]  = x - hw;
        ws_arr(ws, 9)[r]  = y - hl;
        ws_arr(ws, 10)[r] = x + hw;
        ws_arr(ws, 11)[r] = y + hl;
        ws_arr(ws, 12)[r] = bw * bl;
        ws_lv(ws)[r] = (u32)c | ((sc > 0.3f) ? 256u : 0u);
    }
}

// ---------------- 4. suppression bit-matrix (permuted) + transposed diag ----------------
// Row-word layout (for k_nms register tiling):
//   W = i>>6, il = i&63
//   g = W*2048 + (il>>2)*128 + ((il&1)*32 + wj)*2 + ((il>>1)&1)
// diagT[i] = sym-IoU bits of row i restricted to cols j<i of its own 64-block,
// zeroed when i itself is invalid (column validity folded).
__global__ __launch_bounds__(256) void k_suppmat(char* ws) {
    __shared__ float slox[2048], sloy[2048], shix[2048], shiy[2048], sarea[2048];
    __shared__ u32 slv[2048];
    int tid = threadIdx.x;
    for (int i = tid; i < K_PRE; i += 256) {
        slox[i] = ws_arr(ws, 8)[i];
        sloy[i] = ws_arr(ws, 9)[i];
        shix[i] = ws_arr(ws, 10)[i];
        shiy[i] = ws_arr(ws, 11)[i];
        sarea[i] = ws_arr(ws, 12)[i];
        slv[i] = ws_lv(ws)[i];
    }
    __syncthreads();
    int r = tid >> 5, wj = tid & 31;
    int i = blockIdx.x * 8 + r;
    bool diagw = (wj == (i >> 6));
    float lx = slox[i], ly = sloy[i], hx = shix[i], hy = shiy[i], ar = sarea[i];
    u32 li = slv[i] & 0xffu;
    u64 bits = 0, sym = 0;
    for (int s = 0; s < 64; ++s) {
        int off = (s + wj) & 63;       // rotate to avoid LDS bank conflicts
        int j = wj * 64 + off;
        u32 lvj = slv[j];
        bool same = ((lvj & 0xffu) == li) && (j != i);
        bool fwd = same && (j > i) && ((lvj >> 8) != 0u);
        bool bwd = diagw && same && (j < i);
        bool io = false;
        if (fwd || bwd) {
            float iw = fminf(hx, shix[j]) - fmaxf(lx, slox[j]); iw = fmaxf(iw, 0.0f);
            float ih = fminf(hy, shiy[j]) - fmaxf(ly, sloy[j]); ih = fmaxf(ih, 0.0f);
            float inter = iw * ih;
            float un = (ar + sarea[j] - inter) + 1e-6f;
            io = (inter / un) >= 0.5f;
        }
        bits |= ((u64)((io && fwd) ? 1u : 0u)) << off;
        sym  |= ((u64)((io && bwd) ? 1u : 0u)) << off;
    }
    int W = i >> 6, il = i & 63;
    size_t g = (size_t)W * 2048 + (size_t)((il >> 2) * 128 + ((il & 1) * 32 + wj) * 2 + ((il >> 1) & 1));
    ws_mask(ws)[g] = bits;
    if (diagw) {
        u64 dt = sym;
        if (!((slv[i] >> 8) & 1u)) dt = 0;
        ws_diagT(ws)[i] = dt;
    }
}

// ---------------- 5. greedy NMS: Jacobi diag + register cross-block OR ----------------
__device__ __forceinline__ void nms_load_group(const u64* __restrict__ mask, int W, int lane,
                                               u64 (&buf)[32]) {
    const ulonglong2* gp = (const ulonglong2*)(mask + (size_t)W * 2048);
    #pragma unroll
    for (int p = 0; p < 16; ++p) {
        ulonglong2 t = gp[p * 64 + lane];
        buf[2 * p] = t.x;
        buf[2 * p + 1] = t.y;
    }
}

__device__ __forceinline__ void nms_block(u64 (&cur)[32], u64 (&nxt)[32],
                                          u64 dtw, u64& dtw_n,
                                          int W, int lane,
                                          const u64* __restrict__ mask,
                                          const u64* __restrict__ diagT,
                                          u64 valid_dist, u64& remv_dist) {
    if (W + 1 < 32) {
        nms_load_group(mask, W + 1, lane, nxt);      // prefetch next block
        dtw_n = diagT[(W + 1) * 64 + lane];
    }
    u64 av0 = rdlane64(valid_dist, W) & ~rdlane64(remv_dist, W);
    // Jacobi fixed-point on the triangular diag system; unique FP == greedy.
    u64 a = av0;
    #pragma unroll 1
    for (int it = 0; it < 66; ++it) {
        bool self = ((av0 >> lane) & 1ull) != 0ull;
        bool rem = (dtw & a) != 0ull;
        u64 na = __ballot(self && !rem);
        if (na == a) break;
        a = na;
    }
    // cross-block OR of kept rows (a is uniform)
    u64 ksh = a >> (lane >> 5);   // lanes<32: even rows, lanes>=32: odd rows
    u64 partial = 0;
    #pragma unroll
    for (int k = 0; k < 32; ++k) {
        u64 m = (u64)0 - ((ksh >> (2 * k)) & 1ull);
        partial |= cur[k] & m;
    }
    partial |= shflxor32_u64(partial);   // combine even/odd halves
    remv_dist |= partial;                // lane l holds removal word (l&31)
}

__global__ __launch_bounds__(256, 1) void k_nms(char* ws, float* __restrict__ out) {
    const u64* mask = ws_mask(ws);
    const u64* diagT = ws_diagT(ws);
    u32* lv = ws_lv(ws);
    float* score = ws_arr(ws, 0);
    __shared__ u64 validMask[32];
    __shared__ u64 keepMask[32];
    __shared__ u32 sT;
    int tid = threadIdx.x;
    if (tid < 32) validMask[tid] = 0ull;
    __syncthreads();
    for (int i = tid; i < K_PRE; i += 256)
        if ((lv[i] >> 8) & 1u) atomicOr(&validMask[i >> 6], 1ull << (i & 63));
    __syncthreads();

    if (tid < 64) {
        int lane = tid;
        u64 valid_dist = validMask[lane & 31];
        u64 remv_dist = 0ull;
        u64 A[32], B[32];
        u64 dt0, dt1;
        nms_load_group(mask, 0, lane, A);
        dt0 = diagT[lane];
        for (int W = 0; W < 32; W += 2) {
            nms_block(A, B, dt0, dt1, W, lane, mask, diagT, valid_dist, remv_dist);
            nms_block(B, A, dt1, dt0, W + 1, lane, mask, diagT, valid_dist, remv_dist);
        }
        if (lane < 32) keepMask[lane] = valid_dist & ~remv_dist;
    }
    __syncthreads();

    if (tid == 0) {
        u32 T = 0;
        for (int w = 0; w < 32; ++w) T += (u32)__popcll(keepMask[w]);
        sT = T;
    }
    __syncthreads();
    u32 T = sT;
    for (int i = tid; i < K_PRE; i += 256) {
        u64 km = keepMask[i >> 6];
        int bi = i & 63;
        int kp = (int)((km >> bi) & 1ull);
        int rk = 0;
        for (int w = 0; w < (i >> 6); ++w) rk += (int)__popcll(keepMask[w]);
        rk += (int)__popcll(bi ? (km & ((1ull << bi) - 1ull)) : 0ull);
        int slot = -1;
        if (kp) {
            if (rk < MAX_DET) slot = rk;
        } else if ((int)T < MAX_DET) {
            int f = (int)T + (i - rk);
            if (f < MAX_DET) slot = f;
        }
        if (slot >= 0) {
            #pragma unroll
            for (int k = 0; k < 7; ++k)
                out[slot * 8 + k] = kp ? ws_arr(ws, 1 + k)[i] : 0.0f;
            out[slot * 8 + 7] = kp ? score[i] : 0.0f;
            out[8 * MAX_DET + slot] = (float)(lv[i] & 0xffu);
            out[9 * MAX_DET + slot] = kp ? 1.0f : 0.0f;
        }
    }
}

extern "C" void kernel_launch(void* const* d_in, const int* in_sizes, int n_in,
                              void* d_out, int out_size, void* d_ws, size_t ws_size,
                              hipStream_t stream) {
    const float* cls = (const float*)d_in[0];
    const float* bbox = (const float*)d_in[1];
    float* out = (float*)d_out;
    char* ws = (char*)d_ws;
    // zero histogram + meta (counters)
    hipMemsetAsync(ws, 0, NHIST * 4 + 256, stream);
    k_hist<<<256, 512, 0, stream>>>(cls, ws);
    k_compact<<<NCHUNK / 256, 256, 0, stream>>>(cls, ws);   // 160 blocks
    k_rankdec<<<NCAND / 32, 256, 0, stream>>>(bbox, ws);    // 192 blocks
    k_suppmat<<<256, 256, 0, stream>>>(ws);
    k_nms<<<1, 256, 0, stream>>>(ws, out);
}